// Round 2
// baseline (11378.038 us; speedup 1.0000x reference)
//
#include <hip/hip_runtime.h>
#include <hip/hip_bf16.h>
#include <math.h>

#define NN   20000
#define NE   320000
#define TT   24
#define SDIM 16
#define DDIM 8
#define HID  128
#define HEADS 4
#define DPH  32
#define NL   3

// ---------------- CSR build (group edges by dst) ----------------
__global__ void k_count(const int* __restrict__ dst, int* __restrict__ cnt) {
  int e = blockIdx.x * 256 + threadIdx.x;
  if (e < NE) atomicAdd(&cnt[dst[e]], 1);
}

// single block, 20 nodes/thread, one block-scan pass
__global__ __launch_bounds__(1024) void k_scan(const int* __restrict__ cnt,
    int* __restrict__ rowptr, int* __restrict__ cursor) {
  __shared__ int sh[1024];
  int tid = threadIdx.x;
  const int CH = 20;                      // 1024*20 >= NN
  int base = tid * CH;
  int local[CH];
  int s = 0;
  #pragma unroll
  for (int i = 0; i < CH; i++) {
    int idx = base + i;
    int v = (idx < NN) ? cnt[idx] : 0;
    local[i] = s;                         // exclusive within chunk
    s += v;
  }
  sh[tid] = s;
  __syncthreads();
  for (int off = 1; off < 1024; off <<= 1) {
    int tv = (tid >= off) ? sh[tid - off] : 0;
    __syncthreads();
    sh[tid] += tv;
    __syncthreads();
  }
  int pre = (tid > 0) ? sh[tid - 1] : 0;
  #pragma unroll
  for (int i = 0; i < CH; i++) {
    int idx = base + i;
    if (idx < NN) { int e = pre + local[i]; rowptr[idx] = e; cursor[idx] = e; }
  }
  if (tid == 1023) rowptr[NN] = sh[1023];
}

__global__ void k_fill(const int* __restrict__ src, const int* __restrict__ dst,
    int* __restrict__ cursor, int* __restrict__ col) {
  int e = blockIdx.x * 256 + threadIdx.x;
  if (e < NE) {
    int pos = atomicAdd(&cursor[dst[e]], 1);
    col[pos] = src[e];
  }
}

// ---------------- input projection: h[n,:] = [xs[n]|xd_t[n]] @ W + b ----------------
__global__ __launch_bounds__(256) void k_proj(const float* __restrict__ xs,
    const float* __restrict__ xdt, const float* __restrict__ W,
    const float* __restrict__ b, float* __restrict__ h) {
  __shared__ float Ws[24 * HID];
  __shared__ float xin[16][24];
  int tid = threadIdx.x;
  for (int i = tid; i < 24 * HID; i += 256) Ws[i] = W[i];
  int n0 = blockIdx.x * 16;
  for (int i = tid; i < 16 * 24; i += 256) {
    int r = i / 24, c = i % 24;
    int n = n0 + r;
    xin[r][c] = (c < SDIM) ? xs[(size_t)n * SDIM + c]
                           : xdt[(size_t)n * DDIM + (c - SDIM)];
  }
  __syncthreads();
  int ch = tid & 127, rb = (tid >> 7) * 8;
  for (int r = rb; r < rb + 8; r++) {
    float acc = b[ch];
    #pragma unroll
    for (int k = 0; k < 24; k++) acc = fmaf(xin[r][k], Ws[k * HID + ch], acc);
    h[(size_t)(n0 + r) * HID + ch] = acc;
  }
}

// ---------------- fp32 GEMM: C[M,Nout] = [A0|A1][M,K] @ B[K,Nout] ----------------
// A panels have leading dim 128. K = 128 (A1 unused) or 256 (A0 cols 0..127, A1 cols 128..255).
#define GBM 128
#define GBN 64
#define GBK 16
__global__ __launch_bounds__(256) void k_gemm(const float* __restrict__ A0,
    const float* __restrict__ A1, const float* __restrict__ B,
    float* __restrict__ C, int M, int Nout, int K) {
  __shared__ float As[GBK][GBM + 4];
  __shared__ float Bs[GBK][GBN];
  int tid = threadIdx.x;
  int tx = tid & 15, ty = tid >> 4;
  int row0 = blockIdx.x * GBM, col0 = blockIdx.y * GBN;
  float acc[8][4] = {};
  for (int k0 = 0; k0 < K; k0 += GBK) {
    const float* Ap = (k0 < HID) ? A0 : A1;
    int kb = k0 & (HID - 1);
    #pragma unroll
    for (int i = 0; i < 8; i++) {
      int idx = tid + i * 256;
      int r = idx >> 4, kk = idx & 15;
      int gr = row0 + r;
      As[kk][r] = (gr < M) ? Ap[(size_t)gr * HID + kb + kk] : 0.f;
    }
    #pragma unroll
    for (int i = 0; i < 4; i++) {
      int idx = tid + i * 256;
      int kk = idx >> 6, nn = idx & 63;
      Bs[kk][nn] = B[(size_t)(k0 + kk) * Nout + col0 + nn];
    }
    __syncthreads();
    #pragma unroll
    for (int kk = 0; kk < GBK; kk++) {
      float a[8], bb[4];
      #pragma unroll
      for (int i = 0; i < 8; i++) a[i] = As[kk][ty * 8 + i];
      #pragma unroll
      for (int j = 0; j < 4; j++) bb[j] = Bs[kk][tx * 4 + j];
      #pragma unroll
      for (int i = 0; i < 8; i++)
        #pragma unroll
        for (int j = 0; j < 4; j++) acc[i][j] = fmaf(a[i], bb[j], acc[i][j]);
    }
    __syncthreads();
  }
  #pragma unroll
  for (int i = 0; i < 8; i++) {
    int gr = row0 + ty * 8 + i;
    if (gr < M) {
      float4 v = make_float4(acc[i][0], acc[i][1], acc[i][2], acc[i][3]);
      *(float4*)&C[(size_t)gr * Nout + col0 + tx * 4] = v;
    }
  }
}

// ---------------- attention logits: asrc/adst[n, head] ----------------
__global__ __launch_bounds__(256) void k_attn(const float* __restrict__ xp,
    const float* __restrict__ as_, const float* __restrict__ ad_,
    float* __restrict__ asrc, float* __restrict__ adst) {
  int idx = blockIdx.x * 256 + threadIdx.x;       // over N*HEADS
  if (idx >= NN * HEADS) return;
  int hh = idx & 3;
  int n = idx >> 2;
  const float4* xr = (const float4*)(xp + (size_t)n * HID + hh * DPH);
  const float4* av = (const float4*)(as_ + hh * DPH);
  const float4* bv = (const float4*)(ad_ + hh * DPH);
  float s = 0.f, d = 0.f;
  #pragma unroll
  for (int q = 0; q < 8; q++) {
    float4 x = xr[q], a = av[q], b = bv[q];
    s += x.x*a.x + x.y*a.y + x.z*a.z + x.w*a.w;
    d += x.x*b.x + x.y*b.y + x.z*b.z + x.w*b.w;
  }
  asrc[idx] = s;
  adst[idx] = d;
}

// ---------------- GAT aggregation + residual + LayerNorm + ReLU ----------------
// one 64-lane wave per dst-node; online softmax over in-edges (self-loop inline);
// 2 channels per lane (both in the same head: head = lane/16).
__global__ __launch_bounds__(256) void k_aggr(const float* __restrict__ xp,
    float* __restrict__ h, const float* __restrict__ asrc,
    const float* __restrict__ adst, const int* __restrict__ rowptr,
    const int* __restrict__ col, const float* __restrict__ bias,
    const float* __restrict__ lng, const float* __restrict__ lnb) {
  int wid = threadIdx.x >> 6, lane = threadIdx.x & 63;
  int n = blockIdx.x * 4 + wid;
  int hh = lane >> 4;
  float ad = adst[n * HEADS + hh];
  // self-loop
  float e0 = asrc[n * HEADS + hh] + ad;
  e0 = (e0 > 0.f) ? e0 : 0.2f * e0;
  float m = e0, den = 1.f;
  float2 xv = ((const float2*)(xp + (size_t)n * HID))[lane];
  float mg0 = xv.x, mg1 = xv.y;
  int rs = rowptr[n], re = rowptr[n + 1];
  for (int j = rs; j < re; j++) {
    int s = col[j];
    float ev = asrc[s * HEADS + hh] + ad;
    ev = (ev > 0.f) ? ev : 0.2f * ev;
    float mn = fmaxf(m, ev);
    float sc = __expf(m - mn);
    float w  = __expf(ev - mn);
    float2 x2 = ((const float2*)(xp + (size_t)s * HID))[lane];
    den = den * sc + w;
    mg0 = mg0 * sc + w * x2.x;
    mg1 = mg1 * sc + w * x2.y;
    m = mn;
  }
  float inv = 1.f / (den + 1e-16f);
  int c0 = lane * 2;
  size_t hoff = (size_t)n * HID + c0;
  float o0 = mg0 * inv + bias[c0]     + h[hoff];
  float o1 = mg1 * inv + bias[c0 + 1] + h[hoff + 1];
  float s2 = o0 + o1;
  #pragma unroll
  for (int off = 32; off; off >>= 1) s2 += __shfl_xor(s2, off);
  float mu = s2 * (1.f / HID);
  float d0 = o0 - mu, d1 = o1 - mu;
  float v2 = d0 * d0 + d1 * d1;
  #pragma unroll
  for (int off = 32; off; off >>= 1) v2 += __shfl_xor(v2, off);
  float rstd = rsqrtf(v2 * (1.f / HID) + 1e-5f);
  o0 = lng[c0] * d0 * rstd + lnb[c0];
  o1 = lng[c0 + 1] * d1 * rstd + lnb[c0 + 1];
  h[hoff]     = fmaxf(o0, 0.f);
  h[hoff + 1] = fmaxf(o1, 0.f);
}

// ---------------- LSTM: stacked transposed weights [256,512] ----------------
__global__ void k_prepw(const float* __restrict__ Wih, const float* __restrict__ Whh,
    float* __restrict__ Wcat) {
  int idx = blockIdx.x * 256 + threadIdx.x;
  if (idx < 256 * 512) {
    int k = idx >> 9, j = idx & 511;
    Wcat[idx] = (k < HID) ? Wih[(size_t)j * HID + k] : Whh[(size_t)j * HID + (k - HID)];
  }
}

__global__ __launch_bounds__(256) void k_gates(const float* __restrict__ z,
    const float* __restrict__ bih, const float* __restrict__ bhh,
    float* __restrict__ hst, float* __restrict__ cst) {
  int idx = blockIdx.x * 256 + threadIdx.x;
  if (idx >= NN * HID) return;
  int n = idx >> 7, c = idx & 127;
  const float* zr = z + (size_t)n * 512;
  float iv = zr[c]         + bih[c]         + bhh[c];
  float fv = zr[HID + c]   + bih[HID + c]   + bhh[HID + c];
  float gv = zr[2*HID + c] + bih[2*HID + c] + bhh[2*HID + c];
  float ov = zr[3*HID + c] + bih[3*HID + c] + bhh[3*HID + c];
  float si = 1.f / (1.f + __expf(-iv));
  float sf = 1.f / (1.f + __expf(-fv));
  float so = 1.f / (1.f + __expf(-ov));
  float tg = tanhf(gv);
  float cn = sf * cst[idx] + si * tg;
  cst[idx] = cn;
  hst[idx] = so * tanhf(cn);
}

// ---------------- output MLP (fused): relu(h1@W1+b1)@W2+b2 ----------------
__global__ __launch_bounds__(64) void k_mlp(const float* __restrict__ h1,
    const float* __restrict__ W1, const float* __restrict__ b1,
    const float* __restrict__ W2, const float* __restrict__ b2,
    float* __restrict__ out) {
  int n = blockIdx.x, j = threadIdx.x;
  const float* hr = h1 + (size_t)n * HID;
  float acc = b1[j];
  #pragma unroll 8
  for (int k = 0; k < HID; k++) acc = fmaf(hr[k], W1[(size_t)k * 64 + j], acc);
  acc = fmaxf(acc, 0.f);
  float p = acc * W2[j];
  #pragma unroll
  for (int off = 32; off; off >>= 1) p += __shfl_xor(p, off);
  if (j == 0) out[n] = p + b2[0];
}

extern "C" void kernel_launch(void* const* d_in, const int* in_sizes, int n_in,
                              void* d_out, int out_size, void* d_ws, size_t ws_size,
                              hipStream_t stream) {
  const float* xs    = (const float*)d_in[0];
  const float* xd    = (const float*)d_in[1];
  const int*   ei    = (const int*)d_in[2];
  const float* projW = (const float*)d_in[3];
  const float* projb = (const float*)d_in[4];
  const float* gatW  = (const float*)d_in[5];
  const float* attS  = (const float*)d_in[6];
  const float* attD  = (const float*)d_in[7];
  const float* gatb  = (const float*)d_in[8];
  const float* lng   = (const float*)d_in[9];
  const float* lnb   = (const float*)d_in[10];
  const float* Wih0  = (const float*)d_in[11];
  const float* Whh0  = (const float*)d_in[12];
  const float* bih0  = (const float*)d_in[13];
  const float* bhh0  = (const float*)d_in[14];
  const float* Wih1  = (const float*)d_in[15];
  const float* Whh1  = (const float*)d_in[16];
  const float* bih1  = (const float*)d_in[17];
  const float* bhh1  = (const float*)d_in[18];
  const float* oW1   = (const float*)d_in[19];
  const float* ob1   = (const float*)d_in[20];
  const float* oW2   = (const float*)d_in[21];
  const float* ob2   = (const float*)d_in[22];
  float* out = (float*)d_out;

  // -------- workspace layout (~106 MB total) --------
  char* w = (char*)d_ws;
  size_t off = 0;
  auto alloc = [&](size_t bytes) { void* p = w + off; off += (bytes + 255) & ~(size_t)255; return p; };
  float* hcur = (float*)alloc((size_t)NN * HID * 4);        // 10.24 MB
  float* xp   = (float*)alloc((size_t)NN * HID * 4);        // 10.24 MB
  float* asrc = (float*)alloc((size_t)NN * HEADS * 4);
  float* adst = (float*)alloc((size_t)NN * HEADS * 4);
  float* z    = (float*)alloc((size_t)NN * 512 * 4);        // 40.96 MB
  float* h0   = (float*)alloc((size_t)4 * NN * HID * 4);    // h0,c0,h1,c1 contiguous
  float* c0   = h0 + (size_t)NN * HID;
  float* h1   = c0 + (size_t)NN * HID;
  float* c1   = h1 + (size_t)NN * HID;
  float* Wc0  = (float*)alloc((size_t)256 * 512 * 4);
  float* Wc1  = (float*)alloc((size_t)256 * 512 * 4);
  int* cnt    = (int*)alloc((size_t)NN * 4);
  int* rowptr = (int*)alloc((size_t)(NN + 1) * 4);
  int* cursor = (int*)alloc((size_t)NN * 4);
  int* col    = (int*)alloc((size_t)NE * 4);

  const int* esrc = ei;
  const int* edst = ei + NE;

  // -------- CSR (edge_index identical across t and layers) --------
  hipMemsetAsync(cnt, 0, (size_t)NN * 4, stream);
  k_count<<<(NE + 255) / 256, 256, 0, stream>>>(edst, cnt);
  k_scan<<<1, 1024, 0, stream>>>(cnt, rowptr, cursor);
  k_fill<<<(NE + 255) / 256, 256, 0, stream>>>(esrc, edst, cursor, col);

  // -------- LSTM weight prep + state init --------
  k_prepw<<<(256 * 512) / 256, 256, 0, stream>>>(Wih0, Whh0, Wc0);
  k_prepw<<<(256 * 512) / 256, 256, 0, stream>>>(Wih1, Whh1, Wc1);
  hipMemsetAsync(h0, 0, (size_t)4 * NN * HID * 4, stream);

  // -------- per-timestep: GNN (3 GAT layers) then 2 LSTM cells --------
  for (int t = 0; t < TT; t++) {
    k_proj<<<NN / 16, 256, 0, stream>>>(xs, xd + (size_t)t * NN * DDIM, projW, projb, hcur);
    for (int l = 0; l < NL; l++) {
      k_gemm<<<dim3((NN + GBM - 1) / GBM, HID / GBN), 256, 0, stream>>>(
          hcur, nullptr, gatW + (size_t)l * HID * HID, xp, NN, HID, HID);
      k_attn<<<(NN * HEADS + 255) / 256, 256, 0, stream>>>(
          xp, attS + l * HEADS * DPH, attD + l * HEADS * DPH, asrc, adst);
      k_aggr<<<NN / 4, 256, 0, stream>>>(
          xp, hcur, asrc, adst, rowptr, col, gatb + (size_t)l * HID,
          lng + (size_t)l * HID, lnb + (size_t)l * HID);
    }
    k_gemm<<<dim3((NN + GBM - 1) / GBM, 512 / GBN), 256, 0, stream>>>(
        hcur, h0, Wc0, z, NN, 512, 256);
    k_gates<<<(NN * HID) / 256, 256, 0, stream>>>(z, bih0, bhh0, h0, c0);
    k_gemm<<<dim3((NN + GBM - 1) / GBM, 512 / GBN), 256, 0, stream>>>(
        h0, h1, Wc1, z, NN, 512, 256);
    k_gates<<<(NN * HID) / 256, 256, 0, stream>>>(z, bih1, bhh1, h1, c1);
  }

  k_mlp<<<NN, 64, 0, stream>>>(h1, oW1, ob1, oW2, ob2, out);
}

// Round 4
// 6604.219 us; speedup vs baseline: 1.7228x; 1.7228x over previous
//
#include <hip/hip_runtime.h>
#include <hip/hip_bf16.h>
#include <math.h>

#define NN   20000
#define NE   320000
#define TT   24
#define SDIM 16
#define DDIM 8
#define HID  128
#define HEADS 4
#define DPH  32
#define NL   3

typedef unsigned short u16;
typedef unsigned int   u32;
typedef __attribute__((ext_vector_type(8))) short  short8;
typedef __attribute__((ext_vector_type(4))) float  floatx4;

__device__ __forceinline__ u16 f2bf(float x) {          // round-to-nearest-even
  u32 u = __float_as_uint(x);
  return (u16)((u + 0x7fff + ((u >> 16) & 1)) >> 16);
}
__device__ __forceinline__ float bf2f(u16 b) {
  return __uint_as_float(((u32)b) << 16);
}

// ---------------- CSR build (group edges by dst) ----------------
__global__ void k_count(const int* __restrict__ dst, int* __restrict__ cnt) {
  int e = blockIdx.x * 256 + threadIdx.x;
  if (e < NE) atomicAdd(&cnt[dst[e]], 1);
}

__global__ __launch_bounds__(1024) void k_scan(const int* __restrict__ cnt,
    int* __restrict__ rowptr, int* __restrict__ cursor) {
  __shared__ int sh[1024];
  int tid = threadIdx.x;
  const int CH = 20;                      // 1024*20 >= NN
  int base = tid * CH;
  int local[CH];
  int s = 0;
  #pragma unroll
  for (int i = 0; i < CH; i++) {
    int idx = base + i;
    int v = (idx < NN) ? cnt[idx] : 0;
    local[i] = s;
    s += v;
  }
  sh[tid] = s;
  __syncthreads();
  for (int off = 1; off < 1024; off <<= 1) {
    int tv = (tid >= off) ? sh[tid - off] : 0;
    __syncthreads();
    sh[tid] += tv;
    __syncthreads();
  }
  int pre = (tid > 0) ? sh[tid - 1] : 0;
  #pragma unroll
  for (int i = 0; i < CH; i++) {
    int idx = base + i;
    if (idx < NN) { int e = pre + local[i]; rowptr[idx] = e; cursor[idx] = e; }
  }
  if (tid == 1023) rowptr[NN] = sh[1023];
}

__global__ void k_fill(const int* __restrict__ src, const int* __restrict__ dst,
    int* __restrict__ cursor, int* __restrict__ col) {
  int e = blockIdx.x * 256 + threadIdx.x;
  if (e < NE) {
    int pos = atomicAdd(&cursor[dst[e]], 1);
    col[pos] = src[e];
  }
}

// ---------------- weight prep: bf16 (transposed where needed) ----------------
// LSTM: Bt[j][k] = Wih[j][k] (k<128) | Whh[j][k-128]   — native layout, no transpose
__global__ void k_prepw_lstm(const float* __restrict__ Wih, const float* __restrict__ Whh,
    u16* __restrict__ Bt) {
  int idx = blockIdx.x * 256 + threadIdx.x;
  if (idx < 512 * 256) {
    int j = idx >> 8, k = idx & 255;
    float v = (k < 128) ? Wih[(size_t)j * 128 + k] : Whh[(size_t)j * 128 + (k - 128)];
    Bt[idx] = f2bf(v);
  }
}
// GAT: Btg[l][n][k] = gatW[l][k][n]
__global__ void k_prepw_gat(const float* __restrict__ gatW, u16* __restrict__ Btg) {
  int idx = blockIdx.x * 256 + threadIdx.x;
  if (idx < NL * 128 * 128) {
    int l = idx >> 14, r = idx & 16383;
    int n = r >> 7, k = r & 127;
    Btg[idx] = f2bf(gatW[(size_t)l * 16384 + k * 128 + n]);
  }
}

// ---------------- input projection: h[n,:] = [xs[n]|xd_t[n]] @ W + b ----------------
__global__ __launch_bounds__(256) void k_proj(const float* __restrict__ xs,
    const float* __restrict__ xdt, const float* __restrict__ W,
    const float* __restrict__ b, float* __restrict__ h, u16* __restrict__ hbf) {
  __shared__ float Ws[24 * HID];
  __shared__ float xin[16][24];
  int tid = threadIdx.x;
  for (int i = tid; i < 24 * HID; i += 256) Ws[i] = W[i];
  int n0 = blockIdx.x * 16;
  for (int i = tid; i < 16 * 24; i += 256) {
    int r = i / 24, c = i % 24;
    int n = n0 + r;
    xin[r][c] = (c < SDIM) ? xs[(size_t)n * SDIM + c]
                           : xdt[(size_t)n * DDIM + (c - SDIM)];
  }
  __syncthreads();
  int ch = tid & 127, rb = (tid >> 7) * 8;
  for (int r = rb; r < rb + 8; r++) {
    float acc = b[ch];
    #pragma unroll
    for (int k = 0; k < 24; k++) acc = fmaf(xin[r][k], Ws[k * HID + ch], acc);
    size_t o = (size_t)(n0 + r) * HID + ch;
    h[o] = acc;
    hbf[o] = f2bf(acc);
  }
}

// ---------------- bf16 MFMA GEMM: C[M,Nout] = [A0|A1][M,K] @ Bt^T ----------------
// A panels: bf16 [rows][128]. Bt: bf16 [Nout][K]. C: fp32 [M][Nout].
// 256 thr = 4 waves in 2x2; wave computes 64x32 via 16x16x32 bf16 MFMA.
#define TBM 128
#define TBN 64
#define TBK 64
__global__ __launch_bounds__(256) void k_bgemm(const u16* __restrict__ A0,
    const u16* __restrict__ A1, const u16* __restrict__ Bt,
    float* __restrict__ C, int M, int Nout, int K) {
  __shared__ u16 As[TBM][TBK + 8];   // 144B rows = 9*16B -> conflict-free b128
  __shared__ u16 Bs[TBN][TBK + 8];
  int tid = threadIdx.x;
  int wid = tid >> 6, lane = tid & 63;
  int wr = wid >> 1, wc = wid & 1;
  int lrow = lane & 15, lgrp = lane >> 4;
  int row0 = blockIdx.x * TBM, col0 = blockIdx.y * TBN;
  floatx4 acc[4][2] = {};
  for (int k0 = 0; k0 < K; k0 += TBK) {
    const u16* Ap = (k0 < 128) ? A0 : A1;
    int kb = k0 & 127;
    #pragma unroll
    for (int i = 0; i < 4; i++) {                 // A: 128 rows x 8 groups of 8
      int idx = tid + i * 256;
      int r = idx >> 3, g = idx & 7;
      int gr = row0 + r;
      short8 v = {};
      if (gr < M) v = *(const short8*)(Ap + (size_t)gr * 128 + kb + g * 8);
      *(short8*)&As[r][g * 8] = v;
    }
    #pragma unroll
    for (int i = 0; i < 2; i++) {                 // B: 64 rows x 8 groups
      int idx = tid + i * 256;
      int r = idx >> 3, g = idx & 7;
      *(short8*)&Bs[r][g * 8] = *(const short8*)(Bt + (size_t)(col0 + r) * K + k0 + g * 8);
    }
    __syncthreads();
    #pragma unroll
    for (int kk = 0; kk < TBK; kk += 32) {
      short8 bfr[2];
      #pragma unroll
      for (int n = 0; n < 2; n++)
        bfr[n] = *(const short8*)&Bs[wc * 32 + n * 16 + lrow][kk + lgrp * 8];
      #pragma unroll
      for (int m = 0; m < 4; m++) {
        short8 af = *(const short8*)&As[wr * 64 + m * 16 + lrow][kk + lgrp * 8];
        acc[m][0] = __builtin_amdgcn_mfma_f32_16x16x32_bf16(af, bfr[0], acc[m][0], 0, 0, 0);
        acc[m][1] = __builtin_amdgcn_mfma_f32_16x16x32_bf16(af, bfr[1], acc[m][1], 0, 0, 0);
      }
    }
    __syncthreads();
  }
  #pragma unroll
  for (int m = 0; m < 4; m++)
    #pragma unroll
    for (int n = 0; n < 2; n++)
      #pragma unroll
      for (int r = 0; r < 4; r++) {
        int grow = row0 + wr * 64 + m * 16 + lgrp * 4 + r;   // C/D: col=lane&15, row=(lane>>4)*4+reg
        int gcol = col0 + wc * 32 + n * 16 + lrow;
        if (grow < M) C[(size_t)grow * Nout + gcol] = acc[m][n][r];
      }
}

// ---------------- attention logits: asrc/adst[n, head] ----------------
__global__ __launch_bounds__(256) void k_attn(const float* __restrict__ xp,
    const float* __restrict__ as_, const float* __restrict__ ad_,
    float* __restrict__ asrc, float* __restrict__ adst) {
  int idx = blockIdx.x * 256 + threadIdx.x;       // over N*HEADS
  if (idx >= NN * HEADS) return;
  int hh = idx & 3;
  int n = idx >> 2;
  const float4* xr = (const float4*)(xp + (size_t)n * HID + hh * DPH);
  const float4* av = (const float4*)(as_ + hh * DPH);
  const float4* bv = (const float4*)(ad_ + hh * DPH);
  float s = 0.f, d = 0.f;
  #pragma unroll
  for (int q = 0; q < 8; q++) {
    float4 x = xr[q], a = av[q], b = bv[q];
    s += x.x*a.x + x.y*a.y + x.z*a.z + x.w*a.w;
    d += x.x*b.x + x.y*b.y + x.z*b.z + x.w*b.w;
  }
  asrc[idx] = s;
  adst[idx] = d;
}

// ---------------- GAT aggregation + residual + LayerNorm + ReLU ----------------
__global__ __launch_bounds__(256) void k_aggr(const float* __restrict__ xp,
    float* __restrict__ h, u16* __restrict__ hbf, const float* __restrict__ asrc,
    const float* __restrict__ adst, const int* __restrict__ rowptr,
    const int* __restrict__ col, const float* __restrict__ bias,
    const float* __restrict__ lng, const float* __restrict__ lnb) {
  int wid = threadIdx.x >> 6, lane = threadIdx.x & 63;
  int n = blockIdx.x * 4 + wid;
  int hh = lane >> 4;
  float ad = adst[n * HEADS + hh];
  float e0 = asrc[n * HEADS + hh] + ad;            // self-loop
  e0 = (e0 > 0.f) ? e0 : 0.2f * e0;
  float m = e0, den = 1.f;
  float2 xv = ((const float2*)(xp + (size_t)n * HID))[lane];
  float mg0 = xv.x, mg1 = xv.y;
  int rs = rowptr[n], re = rowptr[n + 1];
  for (int j = rs; j < re; j++) {
    int s = col[j];
    float ev = asrc[s * HEADS + hh] + ad;
    ev = (ev > 0.f) ? ev : 0.2f * ev;
    float mn = fmaxf(m, ev);
    float sc = __expf(m - mn);
    float w  = __expf(ev - mn);
    float2 x2 = ((const float2*)(xp + (size_t)s * HID))[lane];
    den = den * sc + w;
    mg0 = mg0 * sc + w * x2.x;
    mg1 = mg1 * sc + w * x2.y;
    m = mn;
  }
  float inv = 1.f / (den + 1e-16f);
  int c0 = lane * 2;
  size_t hoff = (size_t)n * HID + c0;
  float o0 = mg0 * inv + bias[c0]     + h[hoff];
  float o1 = mg1 * inv + bias[c0 + 1] + h[hoff + 1];
  float s2 = o0 + o1;
  #pragma unroll
  for (int off = 32; off; off >>= 1) s2 += __shfl_xor(s2, off);
  float mu = s2 * (1.f / HID);
  float d0 = o0 - mu, d1 = o1 - mu;
  float v2 = d0 * d0 + d1 * d1;
  #pragma unroll
  for (int off = 32; off; off >>= 1) v2 += __shfl_xor(v2, off);
  float rstd = rsqrtf(v2 * (1.f / HID) + 1e-5f);
  o0 = lng[c0] * d0 * rstd + lnb[c0];
  o1 = lng[c0 + 1] * d1 * rstd + lnb[c0 + 1];
  o0 = fmaxf(o0, 0.f);
  o1 = fmaxf(o1, 0.f);
  h[hoff]     = o0;
  h[hoff + 1] = o1;
  *(u32*)(hbf + hoff) = (u32)f2bf(o0) | ((u32)f2bf(o1) << 16);
}

// ---------------- LSTM gates: c fp32, h out bf16 ----------------
__global__ __launch_bounds__(256) void k_gates(const float* __restrict__ z,
    const float* __restrict__ bih, const float* __restrict__ bhh,
    float* __restrict__ cst, u16* __restrict__ hbf) {
  int idx = blockIdx.x * 256 + threadIdx.x;
  if (idx >= NN * HID) return;
  int n = idx >> 7, c = idx & 127;
  const float* zr = z + (size_t)n * 512;
  float iv = zr[c]         + bih[c]         + bhh[c];
  float fv = zr[HID + c]   + bih[HID + c]   + bhh[HID + c];
  float gv = zr[2*HID + c] + bih[2*HID + c] + bhh[2*HID + c];
  float ov = zr[3*HID + c] + bih[3*HID + c] + bhh[3*HID + c];
  float si = 1.f / (1.f + __expf(-iv));
  float sf = 1.f / (1.f + __expf(-fv));
  float so = 1.f / (1.f + __expf(-ov));
  float tg = tanhf(gv);
  float cn = sf * cst[idx] + si * tg;
  cst[idx] = cn;
  hbf[idx] = f2bf(so * tanhf(cn));
}

// ---------------- output MLP: relu(h1@W1+b1)@W2+b2 ----------------
__global__ __launch_bounds__(64) void k_mlp(const u16* __restrict__ h1,
    const float* __restrict__ W1, const float* __restrict__ b1,
    const float* __restrict__ W2, const float* __restrict__ b2,
    float* __restrict__ out) {
  int n = blockIdx.x, j = threadIdx.x;
  const u16* hr = h1 + (size_t)n * HID;
  float acc = b1[j];
  #pragma unroll 8
  for (int k = 0; k < HID; k++) acc = fmaf(bf2f(hr[k]), W1[(size_t)k * 64 + j], acc);
  acc = fmaxf(acc, 0.f);
  float p = acc * W2[j];
  #pragma unroll
  for (int off = 32; off; off >>= 1) p += __shfl_xor(p, off);
  if (j == 0) out[n] = p + b2[0];
}

extern "C" void kernel_launch(void* const* d_in, const int* in_sizes, int n_in,
                              void* d_out, int out_size, void* d_ws, size_t ws_size,
                              hipStream_t stream) {
  const float* xs    = (const float*)d_in[0];
  const float* xd    = (const float*)d_in[1];
  const int*   ei    = (const int*)d_in[2];
  const float* projW = (const float*)d_in[3];
  const float* projb = (const float*)d_in[4];
  const float* gatW  = (const float*)d_in[5];
  const float* attS  = (const float*)d_in[6];
  const float* attD  = (const float*)d_in[7];
  const float* gatb  = (const float*)d_in[8];
  const float* lng   = (const float*)d_in[9];
  const float* lnb   = (const float*)d_in[10];
  const float* Wih0  = (const float*)d_in[11];
  const float* Whh0  = (const float*)d_in[12];
  const float* bih0  = (const float*)d_in[13];
  const float* bhh0  = (const float*)d_in[14];
  const float* Wih1  = (const float*)d_in[15];
  const float* Whh1  = (const float*)d_in[16];
  const float* bih1  = (const float*)d_in[17];
  const float* bhh1  = (const float*)d_in[18];
  const float* oW1   = (const float*)d_in[19];
  const float* ob1   = (const float*)d_in[20];
  const float* oW2   = (const float*)d_in[21];
  const float* ob2   = (const float*)d_in[22];
  float* out = (float*)d_out;

  // -------- workspace layout (~99 MB) --------
  char* w = (char*)d_ws;
  size_t off = 0;
  auto alloc = [&](size_t bytes) { void* p = w + off; off += (bytes + 255) & ~(size_t)255; return p; };
  float* hcur  = (float*)alloc((size_t)NN * HID * 4);        // fp32 h (residual path)
  u16*   hbf   = (u16*)  alloc((size_t)NN * HID * 2);        // bf16 mirror (GEMM A)
  float* xp    = (float*)alloc((size_t)NN * HID * 4);
  float* asrc  = (float*)alloc((size_t)NN * HEADS * 4);
  float* adst  = (float*)alloc((size_t)NN * HEADS * 4);
  float* z     = (float*)alloc((size_t)NN * 512 * 4);
  float* c01   = (float*)alloc((size_t)2 * NN * HID * 4);    // c0,c1
  float* c0 = c01, *c1 = c01 + (size_t)NN * HID;
  u16*   hbf01 = (u16*)  alloc((size_t)2 * NN * HID * 2);    // h0,h1 (bf16 only)
  u16*   h0bf = hbf01, *h1bf = hbf01 + (size_t)NN * HID;
  u16*   Wc0bf = (u16*)alloc((size_t)512 * 256 * 2);
  u16*   Wc1bf = (u16*)alloc((size_t)512 * 256 * 2);
  u16*   gatWbf= (u16*)alloc((size_t)NL * 128 * 128 * 2);
  int* cnt    = (int*)alloc((size_t)NN * 4);
  int* rowptr = (int*)alloc((size_t)(NN + 1) * 4);
  int* cursor = (int*)alloc((size_t)NN * 4);
  int* col    = (int*)alloc((size_t)NE * 4);

  const int* esrc = ei;
  const int* edst = ei + NE;

  // -------- CSR (edge_index identical across t and layers) --------
  hipMemsetAsync(cnt, 0, (size_t)NN * 4, stream);
  k_count<<<(NE + 255) / 256, 256, 0, stream>>>(edst, cnt);
  k_scan<<<1, 1024, 0, stream>>>(cnt, rowptr, cursor);
  k_fill<<<(NE + 255) / 256, 256, 0, stream>>>(esrc, edst, cursor, col);

  // -------- weight prep + state init --------
  k_prepw_lstm<<<(512 * 256) / 256, 256, 0, stream>>>(Wih0, Whh0, Wc0bf);
  k_prepw_lstm<<<(512 * 256) / 256, 256, 0, stream>>>(Wih1, Whh1, Wc1bf);
  k_prepw_gat<<<(NL * 128 * 128) / 256, 256, 0, stream>>>(gatW, gatWbf);
  hipMemsetAsync(c01, 0, (size_t)2 * NN * HID * 4, stream);
  hipMemsetAsync(hbf01, 0, (size_t)2 * NN * HID * 2, stream);

  // -------- per-timestep: GNN (3 GAT layers) then 2 LSTM cells --------
  for (int t = 0; t < TT; t++) {
    k_proj<<<NN / 16, 256, 0, stream>>>(xs, xd + (size_t)t * NN * DDIM, projW, projb, hcur, hbf);
    for (int l = 0; l < NL; l++) {
      k_bgemm<<<dim3((NN + TBM - 1) / TBM, HID / TBN), 256, 0, stream>>>(
          hbf, hbf, gatWbf + (size_t)l * 128 * 128, xp, NN, HID, HID);
      k_attn<<<(NN * HEADS + 255) / 256, 256, 0, stream>>>(
          xp, attS + l * HEADS * DPH, attD + l * HEADS * DPH, asrc, adst);
      k_aggr<<<NN / 4, 256, 0, stream>>>(
          xp, hcur, hbf, asrc, adst, rowptr, col, gatb + (size_t)l * HID,
          lng + (size_t)l * HID, lnb + (size_t)l * HID);
    }
    k_bgemm<<<dim3((NN + TBM - 1) / TBM, 512 / TBN), 256, 0, stream>>>(
        hbf, h0bf, Wc0bf, z, NN, 512, 256);
    k_gates<<<(NN * HID) / 256, 256, 0, stream>>>(z, bih0, bhh0, c0, h0bf);
    k_bgemm<<<dim3((NN + TBM - 1) / TBM, 512 / TBN), 256, 0, stream>>>(
        h0bf, h1bf, Wc1bf, z, NN, 512, 256);
    k_gates<<<(NN * HID) / 256, 256, 0, stream>>>(z, bih1, bhh1, c1, h1bf);
  }

  k_mlp<<<NN, 64, 0, stream>>>(h1bf, oW1, ob1, oW2, ob2, out);
}

// Round 5
// 5231.349 us; speedup vs baseline: 2.1750x; 1.2624x over previous
//
#include <hip/hip_runtime.h>
#include <hip/hip_bf16.h>
#include <math.h>

#define NN   20000
#define NE   320000
#define TT   24
#define SDIM 16
#define DDIM 8
#define HID  128
#define HEADS 4
#define DPH  32
#define NL   3

typedef unsigned short u16;
typedef unsigned int   u32;
typedef __attribute__((ext_vector_type(8))) short  short8;
typedef __attribute__((ext_vector_type(4))) float  floatx4;

__device__ __forceinline__ u16 f2bf(float x) {          // round-to-nearest-even
  u32 u = __float_as_uint(x);
  return (u16)((u + 0x7fff + ((u >> 16) & 1)) >> 16);
}
__device__ __forceinline__ float bf2f(u16 b) {
  return __uint_as_float(((u32)b) << 16);
}

// ---------------- CSR build (group edges by dst) ----------------
__global__ void k_count(const int* __restrict__ dst, int* __restrict__ cnt) {
  int e = blockIdx.x * 256 + threadIdx.x;
  if (e < NE) atomicAdd(&cnt[dst[e]], 1);
}

__global__ __launch_bounds__(1024) void k_scan(const int* __restrict__ cnt,
    int* __restrict__ rowptr, int* __restrict__ cursor) {
  __shared__ int sh[1024];
  int tid = threadIdx.x;
  const int CH = 20;                      // 1024*20 >= NN
  int base = tid * CH;
  int local[CH];
  int s = 0;
  #pragma unroll
  for (int i = 0; i < CH; i++) {
    int idx = base + i;
    int v = (idx < NN) ? cnt[idx] : 0;
    local[i] = s;
    s += v;
  }
  sh[tid] = s;
  __syncthreads();
  for (int off = 1; off < 1024; off <<= 1) {
    int tv = (tid >= off) ? sh[tid - off] : 0;
    __syncthreads();
    sh[tid] += tv;
    __syncthreads();
  }
  int pre = (tid > 0) ? sh[tid - 1] : 0;
  #pragma unroll
  for (int i = 0; i < CH; i++) {
    int idx = base + i;
    if (idx < NN) { int e = pre + local[i]; rowptr[idx] = e; cursor[idx] = e; }
  }
  if (tid == 1023) rowptr[NN] = sh[1023];
}

__global__ void k_fill(const int* __restrict__ src, const int* __restrict__ dst,
    int* __restrict__ cursor, int* __restrict__ col) {
  int e = blockIdx.x * 256 + threadIdx.x;
  if (e < NE) {
    int pos = atomicAdd(&cursor[dst[e]], 1);
    col[pos] = src[e];
  }
}

// ---------------- weight prep ----------------
// LSTM weights, GATE-INTERLEAVED: Bt[4c+g][k] = W[g*128+c][k], W = [Wih | Whh]
__global__ void k_prepw_lstm(const float* __restrict__ Wih, const float* __restrict__ Whh,
    u16* __restrict__ Bt) {
  int idx = blockIdx.x * 256 + threadIdx.x;
  if (idx < 512 * 256) {
    int jp = idx >> 8, k = idx & 255;
    int c = jp >> 2, g = jp & 3;
    int j = g * 128 + c;
    float v = (k < 128) ? Wih[(size_t)j * 128 + k] : Whh[(size_t)j * 128 + (k - 128)];
    Bt[idx] = f2bf(v);
  }
}
// combined bias, gate-interleaved: bs[4c+g] = bih[g*128+c] + bhh[g*128+c]; 2 cells
__global__ void k_prepb(const float* __restrict__ bih0, const float* __restrict__ bhh0,
    const float* __restrict__ bih1, const float* __restrict__ bhh1,
    float* __restrict__ bs01) {
  int t = threadIdx.x;               // 512 per block, blockIdx.x = cell
  const float* bih = blockIdx.x ? bih1 : bih0;
  const float* bhh = blockIdx.x ? bhh1 : bhh0;
  int c = t >> 2, g = t & 3;
  bs01[blockIdx.x * 512 + t] = bih[g * 128 + c] + bhh[g * 128 + c];
}
// GAT: Btg[l][n][k] = gatW[l][k][n]
__global__ void k_prepw_gat(const float* __restrict__ gatW, u16* __restrict__ Btg) {
  int idx = blockIdx.x * 256 + threadIdx.x;
  if (idx < NL * 128 * 128) {
    int l = idx >> 14, r = idx & 16383;
    int n = r >> 7, k = r & 127;
    Btg[idx] = f2bf(gatW[(size_t)l * 16384 + k * 128 + n]);
  }
}

// ---------------- input projection: h[n,:] = [xs[n]|xd_t[n]] @ W + b ----------------
__global__ __launch_bounds__(256) void k_proj(const float* __restrict__ xs,
    const float* __restrict__ xdt, const float* __restrict__ W,
    const float* __restrict__ b, float* __restrict__ h, u16* __restrict__ hbf) {
  __shared__ float Ws[24 * HID];
  __shared__ float xin[16][24];
  int tid = threadIdx.x;
  for (int i = tid; i < 24 * HID; i += 256) Ws[i] = W[i];
  int n0 = blockIdx.x * 16;
  for (int i = tid; i < 16 * 24; i += 256) {
    int r = i / 24, c = i % 24;
    int n = n0 + r;
    xin[r][c] = (c < SDIM) ? xs[(size_t)n * SDIM + c]
                           : xdt[(size_t)n * DDIM + (c - SDIM)];
  }
  __syncthreads();
  int ch = tid & 127, rb = (tid >> 7) * 8;
  for (int r = rb; r < rb + 8; r++) {
    float acc = b[ch];
    #pragma unroll
    for (int k = 0; k < 24; k++) acc = fmaf(xin[r][k], Ws[k * HID + ch], acc);
    size_t o = (size_t)(n0 + r) * HID + ch;
    h[o] = acc;
    hbf[o] = f2bf(acc);
  }
}

#define TBM 128
#define TBN 64
#define TBK 64

// ---------------- GAT GEMM + fused attention-logit epilogue ----------------
// xp[M,128] = A[M,128] @ Bt^T ; asrc/adst[n,h] = dot(xp[n, h*32:+32], att)
__global__ __launch_bounds__(256) void k_bgemm_gat(const u16* __restrict__ A,
    const u16* __restrict__ Bt, const float* __restrict__ as_,
    const float* __restrict__ ad_, float* __restrict__ xp,
    float* __restrict__ asrc, float* __restrict__ adst, int M) {
  __shared__ u16 As[TBM][TBK + 8];
  __shared__ u16 Bs[TBN][TBK + 8];
  int tid = threadIdx.x;
  int wid = tid >> 6, lane = tid & 63;
  int wr = wid >> 1, wc = wid & 1;
  int lrow = lane & 15, lgrp = lane >> 4;
  int row0 = blockIdx.x * TBM, col0 = blockIdx.y * TBN;
  floatx4 acc[4][2] = {};
  for (int k0 = 0; k0 < 128; k0 += TBK) {
    #pragma unroll
    for (int i = 0; i < 4; i++) {
      int idx = tid + i * 256;
      int r = idx >> 3, g = idx & 7;
      int gr = row0 + r;
      short8 v = {};
      if (gr < M) v = *(const short8*)(A + (size_t)gr * 128 + k0 + g * 8);
      *(short8*)&As[r][g * 8] = v;
    }
    #pragma unroll
    for (int i = 0; i < 2; i++) {
      int idx = tid + i * 256;
      int r = idx >> 3, g = idx & 7;
      *(short8*)&Bs[r][g * 8] = *(const short8*)(Bt + (size_t)(col0 + r) * 128 + k0 + g * 8);
    }
    __syncthreads();
    #pragma unroll
    for (int kk = 0; kk < TBK; kk += 32) {
      short8 bfr[2];
      #pragma unroll
      for (int n = 0; n < 2; n++)
        bfr[n] = *(const short8*)&Bs[wc * 32 + n * 16 + lrow][kk + lgrp * 8];
      #pragma unroll
      for (int m = 0; m < 4; m++) {
        short8 af = *(const short8*)&As[wr * 64 + m * 16 + lrow][kk + lgrp * 8];
        acc[m][0] = __builtin_amdgcn_mfma_f32_16x16x32_bf16(af, bfr[0], acc[m][0], 0, 0, 0);
        acc[m][1] = __builtin_amdgcn_mfma_f32_16x16x32_bf16(af, bfr[1], acc[m][1], 0, 0, 0);
      }
    }
    __syncthreads();
  }
  // epilogue: xp write + attn logits (wave's 32-col slab = one head)
  int head = (col0 >> 5) + wc;
  float as0 = as_[head * 32 + lrow], as1 = as_[head * 32 + 16 + lrow];
  float ad0 = ad_[head * 32 + lrow], ad1 = ad_[head * 32 + 16 + lrow];
  #pragma unroll
  for (int m = 0; m < 4; m++) {
    #pragma unroll
    for (int r = 0; r < 4; r++) {
      int grow = row0 + wr * 64 + m * 16 + lgrp * 4 + r;
      float v0 = acc[m][0][r], v1 = acc[m][1][r];
      if (grow < M) {
        xp[(size_t)grow * HID + col0 + wc * 32 + lrow]      = v0;
        xp[(size_t)grow * HID + col0 + wc * 32 + 16 + lrow] = v1;
      }
      float ps = v0 * as0 + v1 * as1;
      float pd = v0 * ad0 + v1 * ad1;
      #pragma unroll
      for (int off = 1; off < 16; off <<= 1) {
        ps += __shfl_xor(ps, off);
        pd += __shfl_xor(pd, off);
      }
      if (lrow == 0 && grow < M) {
        asrc[grow * HEADS + head] = ps;
        adst[grow * HEADS + head] = pd;
      }
    }
  }
}

// ---------------- LSTM GEMM + fused gate epilogue ----------------
// z = [A0|A1][M,256] @ Bt^T (Bt gate-interleaved [512,256]); then gates in-block.
// Writes c (in-place, block-exclusive) and h (bf16) to hout (ping-pong buffer).
__global__ __launch_bounds__(256) void k_bgemm_lstm(const u16* __restrict__ A0,
    const u16* __restrict__ A1, const u16* __restrict__ Bt,
    const float* __restrict__ bs, float* __restrict__ cst,
    u16* __restrict__ hout, int M) {
  __shared__ __align__(16) char smem[34816];   // max(As+Bs=27648, zs=128*68*4=34816)
  u16 (*As)[TBK + 8] = (u16(*)[TBK + 8])smem;
  u16 (*Bs)[TBK + 8] = (u16(*)[TBK + 8])(smem + TBM * (TBK + 8) * 2);
  float (*zs)[68] = (float(*)[68])smem;
  int tid = threadIdx.x;
  int wid = tid >> 6, lane = tid & 63;
  int wr = wid >> 1, wc = wid & 1;
  int lrow = lane & 15, lgrp = lane >> 4;
  int row0 = blockIdx.x * TBM, col0 = blockIdx.y * TBN;
  floatx4 acc[4][2] = {};
  for (int k0 = 0; k0 < 256; k0 += TBK) {
    const u16* Ap = (k0 < 128) ? A0 : A1;
    int kb = k0 & 127;
    #pragma unroll
    for (int i = 0; i < 4; i++) {
      int idx = tid + i * 256;
      int r = idx >> 3, g = idx & 7;
      int gr = row0 + r;
      short8 v = {};
      if (gr < M) v = *(const short8*)(Ap + (size_t)gr * 128 + kb + g * 8);
      *(short8*)&As[r][g * 8] = v;
    }
    #pragma unroll
    for (int i = 0; i < 2; i++) {
      int idx = tid + i * 256;
      int r = idx >> 3, g = idx & 7;
      *(short8*)&Bs[r][g * 8] = *(const short8*)(Bt + (size_t)(col0 + r) * 256 + k0 + g * 8);
    }
    __syncthreads();
    #pragma unroll
    for (int kk = 0; kk < TBK; kk += 32) {
      short8 bfr[2];
      #pragma unroll
      for (int n = 0; n < 2; n++)
        bfr[n] = *(const short8*)&Bs[wc * 32 + n * 16 + lrow][kk + lgrp * 8];
      #pragma unroll
      for (int m = 0; m < 4; m++) {
        short8 af = *(const short8*)&As[wr * 64 + m * 16 + lrow][kk + lgrp * 8];
        acc[m][0] = __builtin_amdgcn_mfma_f32_16x16x32_bf16(af, bfr[0], acc[m][0], 0, 0, 0);
        acc[m][1] = __builtin_amdgcn_mfma_f32_16x16x32_bf16(af, bfr[1], acc[m][1], 0, 0, 0);
      }
    }
    __syncthreads();
  }
  // stage z-tile to LDS (all waves done reading As/Bs after final sync)
  #pragma unroll
  for (int m = 0; m < 4; m++)
    #pragma unroll
    for (int n = 0; n < 2; n++)
      #pragma unroll
      for (int r = 0; r < 4; r++)
        zs[wr * 64 + m * 16 + lgrp * 4 + r][wc * 32 + n * 16 + lrow] = acc[m][n][r];
  __syncthreads();
  // gate epilogue: 128 rows x 16 channels per block
  int ch0 = blockIdx.y * 16;
  #pragma unroll
  for (int it = 0; it < 8; it++) {
    int o = tid + it * 256;
    int r = o >> 4, lc = o & 15;
    int grow = row0 + r;
    if (grow < M) {
      float4 zi = *(float4*)&zs[r][lc * 4];
      int ch = ch0 + lc;
      size_t gi = (size_t)grow * HID + ch;
      float ii = zi.x + bs[4 * ch + 0];
      float ff = zi.y + bs[4 * ch + 1];
      float gg = zi.z + bs[4 * ch + 2];
      float oo = zi.w + bs[4 * ch + 3];
      float si = 1.f / (1.f + __expf(-ii));
      float sf = 1.f / (1.f + __expf(-ff));
      float so = 1.f / (1.f + __expf(-oo));
      float tg = tanhf(gg);
      float cn = sf * cst[gi] + si * tg;
      cst[gi] = cn;
      hout[gi] = f2bf(so * tanhf(cn));
    }
  }
}

// ---------------- GAT aggregation + residual + LayerNorm + ReLU ----------------
__global__ __launch_bounds__(256) void k_aggr(const float* __restrict__ xp,
    float* __restrict__ h, u16* __restrict__ hbf, const float* __restrict__ asrc,
    const float* __restrict__ adst, const int* __restrict__ rowptr,
    const int* __restrict__ col, const float* __restrict__ bias,
    const float* __restrict__ lng, const float* __restrict__ lnb) {
  int wid = threadIdx.x >> 6, lane = threadIdx.x & 63;
  int n = blockIdx.x * 4 + wid;
  int hh = lane >> 4;
  float ad = adst[n * HEADS + hh];
  float e0 = asrc[n * HEADS + hh] + ad;            // self-loop
  e0 = (e0 > 0.f) ? e0 : 0.2f * e0;
  float m = e0, den = 1.f;
  float2 xv = ((const float2*)(xp + (size_t)n * HID))[lane];
  float mg0 = xv.x, mg1 = xv.y;
  int rs = rowptr[n], re = rowptr[n + 1];
  int j = rs;
  for (; j + 1 < re; j += 2) {                     // 2-edge unrolled online softmax
    int s0 = col[j], s1 = col[j + 1];
    float ev0 = asrc[s0 * HEADS + hh] + ad;
    float ev1 = asrc[s1 * HEADS + hh] + ad;
    ev0 = (ev0 > 0.f) ? ev0 : 0.2f * ev0;
    ev1 = (ev1 > 0.f) ? ev1 : 0.2f * ev1;
    float2 x0 = ((const float2*)(xp + (size_t)s0 * HID))[lane];
    float2 x1 = ((const float2*)(xp + (size_t)s1 * HID))[lane];
    float mn = fmaxf(m, fmaxf(ev0, ev1));
    float sc = __expf(m - mn);
    float w0 = __expf(ev0 - mn);
    float w1 = __expf(ev1 - mn);
    den = den * sc + w0 + w1;
    mg0 = mg0 * sc + w0 * x0.x + w1 * x1.x;
    mg1 = mg1 * sc + w0 * x0.y + w1 * x1.y;
    m = mn;
  }
  if (j < re) {
    int s0 = col[j];
    float ev = asrc[s0 * HEADS + hh] + ad;
    ev = (ev > 0.f) ? ev : 0.2f * ev;
    float2 x2 = ((const float2*)(xp + (size_t)s0 * HID))[lane];
    float mn = fmaxf(m, ev);
    float sc = __expf(m - mn);
    float w  = __expf(ev - mn);
    den = den * sc + w;
    mg0 = mg0 * sc + w * x2.x;
    mg1 = mg1 * sc + w * x2.y;
    m = mn;
  }
  float inv = 1.f / (den + 1e-16f);
  int c0 = lane * 2;
  size_t hoff = (size_t)n * HID + c0;
  float o0 = mg0 * inv + bias[c0]     + h[hoff];
  float o1 = mg1 * inv + bias[c0 + 1] + h[hoff + 1];
  float s2 = o0 + o1;
  #pragma unroll
  for (int off = 32; off; off >>= 1) s2 += __shfl_xor(s2, off);
  float mu = s2 * (1.f / HID);
  float d0 = o0 - mu, d1 = o1 - mu;
  float v2 = d0 * d0 + d1 * d1;
  #pragma unroll
  for (int off = 32; off; off >>= 1) v2 += __shfl_xor(v2, off);
  float rstd = rsqrtf(v2 * (1.f / HID) + 1e-5f);
  o0 = lng[c0] * d0 * rstd + lnb[c0];
  o1 = lng[c0 + 1] * d1 * rstd + lnb[c0 + 1];
  o0 = fmaxf(o0, 0.f);
  o1 = fmaxf(o1, 0.f);
  h[hoff]     = o0;
  h[hoff + 1] = o1;
  *(u32*)(hbf + hoff) = (u32)f2bf(o0) | ((u32)f2bf(o1) << 16);
}

// ---------------- output MLP: relu(h1@W1+b1)@W2+b2 ----------------
__global__ __launch_bounds__(64) void k_mlp(const u16* __restrict__ h1,
    const float* __restrict__ W1, const float* __restrict__ b1,
    const float* __restrict__ W2, const float* __restrict__ b2,
    float* __restrict__ out) {
  int n = blockIdx.x, j = threadIdx.x;
  const u16* hr = h1 + (size_t)n * HID;
  float acc = b1[j];
  #pragma unroll 8
  for (int k = 0; k < HID; k++) acc = fmaf(bf2f(hr[k]), W1[(size_t)k * 64 + j], acc);
  acc = fmaxf(acc, 0.f);
  float p = acc * W2[j];
  #pragma unroll
  for (int off = 32; off; off >>= 1) p += __shfl_xor(p, off);
  if (j == 0) out[n] = p + b2[0];
}

extern "C" void kernel_launch(void* const* d_in, const int* in_sizes, int n_in,
                              void* d_out, int out_size, void* d_ws, size_t ws_size,
                              hipStream_t stream) {
  const float* xs    = (const float*)d_in[0];
  const float* xd    = (const float*)d_in[1];
  const int*   ei    = (const int*)d_in[2];
  const float* projW = (const float*)d_in[3];
  const float* projb = (const float*)d_in[4];
  const float* gatW  = (const float*)d_in[5];
  const float* attS  = (const float*)d_in[6];
  const float* attD  = (const float*)d_in[7];
  const float* gatb  = (const float*)d_in[8];
  const float* lng   = (const float*)d_in[9];
  const float* lnb   = (const float*)d_in[10];
  const float* Wih0  = (const float*)d_in[11];
  const float* Whh0  = (const float*)d_in[12];
  const float* bih0  = (const float*)d_in[13];
  const float* bhh0  = (const float*)d_in[14];
  const float* Wih1  = (const float*)d_in[15];
  const float* Whh1  = (const float*)d_in[16];
  const float* bih1  = (const float*)d_in[17];
  const float* bhh1  = (const float*)d_in[18];
  const float* oW1   = (const float*)d_in[19];
  const float* ob1   = (const float*)d_in[20];
  const float* oW2   = (const float*)d_in[21];
  const float* ob2   = (const float*)d_in[22];
  float* out = (float*)d_out;

  // -------- workspace layout (~70 MB) --------
  char* w = (char*)d_ws;
  size_t off = 0;
  auto alloc = [&](size_t bytes) { void* p = w + off; off += (bytes + 255) & ~(size_t)255; return p; };
  float* hcur  = (float*)alloc((size_t)NN * HID * 4);        // fp32 h (residual path)
  u16*   hbf   = (u16*)  alloc((size_t)NN * HID * 2);        // bf16 mirror (GEMM A)
  float* xp    = (float*)alloc((size_t)NN * HID * 4);
  float* asrc  = (float*)alloc((size_t)NN * HEADS * 4);
  float* adst  = (float*)alloc((size_t)NN * HEADS * 4);
  float* c01   = (float*)alloc((size_t)2 * NN * HID * 4);    // c0,c1
  float* c0 = c01, *c1 = c01 + (size_t)NN * HID;
  u16*   h0p   = (u16*)  alloc((size_t)2 * NN * HID * 2);    // h0 ping-pong
  u16*   h1p   = (u16*)  alloc((size_t)2 * NN * HID * 2);    // h1 ping-pong
  u16*   h0buf[2] = { h0p, h0p + (size_t)NN * HID };
  u16*   h1buf[2] = { h1p, h1p + (size_t)NN * HID };
  u16*   Wc0bf = (u16*)alloc((size_t)512 * 256 * 2);
  u16*   Wc1bf = (u16*)alloc((size_t)512 * 256 * 2);
  float* bs01  = (float*)alloc((size_t)1024 * 4);
  float* bs0 = bs01, *bs1 = bs01 + 512;
  u16*   gatWbf= (u16*)alloc((size_t)NL * 128 * 128 * 2);
  int* cnt    = (int*)alloc((size_t)NN * 4);
  int* rowptr = (int*)alloc((size_t)(NN + 1) * 4);
  int* cursor = (int*)alloc((size_t)NN * 4);
  int* col    = (int*)alloc((size_t)NE * 4);

  const int* esrc = ei;
  const int* edst = ei + NE;

  // -------- CSR (edge_index identical across t and layers) --------
  hipMemsetAsync(cnt, 0, (size_t)NN * 4, stream);
  k_count<<<(NE + 255) / 256, 256, 0, stream>>>(edst, cnt);
  k_scan<<<1, 1024, 0, stream>>>(cnt, rowptr, cursor);
  k_fill<<<(NE + 255) / 256, 256, 0, stream>>>(esrc, edst, cursor, col);

  // -------- weight/bias prep + state init --------
  k_prepw_lstm<<<(512 * 256) / 256, 256, 0, stream>>>(Wih0, Whh0, Wc0bf);
  k_prepw_lstm<<<(512 * 256) / 256, 256, 0, stream>>>(Wih1, Whh1, Wc1bf);
  k_prepb<<<2, 512, 0, stream>>>(bih0, bhh0, bih1, bhh1, bs01);
  k_prepw_gat<<<(NL * 128 * 128) / 256, 256, 0, stream>>>(gatW, gatWbf);
  hipMemsetAsync(c01, 0, (size_t)2 * NN * HID * 4, stream);
  hipMemsetAsync(h0buf[0], 0, (size_t)NN * HID * 2, stream);
  hipMemsetAsync(h1buf[0], 0, (size_t)NN * HID * 2, stream);

  // -------- per-timestep: GNN (3 GAT layers) then 2 fused LSTM cells --------
  const int gx = (NN + TBM - 1) / TBM;   // 157
  for (int t = 0; t < TT; t++) {
    int pi = t & 1;
    k_proj<<<NN / 16, 256, 0, stream>>>(xs, xd + (size_t)t * NN * DDIM, projW, projb, hcur, hbf);
    for (int l = 0; l < NL; l++) {
      k_bgemm_gat<<<dim3(gx, 2), 256, 0, stream>>>(
          hbf, gatWbf + (size_t)l * 128 * 128,
          attS + l * HEADS * DPH, attD + l * HEADS * DPH,
          xp, asrc, adst, NN);
      k_aggr<<<NN / 4, 256, 0, stream>>>(
          xp, hcur, hbf, asrc, adst, rowptr, col, gatb + (size_t)l * HID,
          lng + (size_t)l * HID, lnb + (size_t)l * HID);
    }
    // cell 0: A=[h_gnn | h0_old] -> writes c0, h0_new (ping-pong)
    k_bgemm_lstm<<<dim3(gx, 8), 256, 0, stream>>>(
        hbf, h0buf[pi], Wc0bf, bs0, c0, h0buf[pi ^ 1], NN);
    // cell 1: A=[h0_new | h1_old] -> writes c1, h1_new
    k_bgemm_lstm<<<dim3(gx, 8), 256, 0, stream>>>(
        h0buf[pi ^ 1], h1buf[pi], Wc1bf, bs1, c1, h1buf[pi ^ 1], NN);
  }

  // TT even -> final h1 lives in h1buf[0]
  k_mlp<<<NN, 64, 0, stream>>>(h1buf[0], oW1, ob1, oW2, ob2, out);
}

// Round 6
// 4152.718 us; speedup vs baseline: 2.7399x; 1.2597x over previous
//
#include <hip/hip_runtime.h>
#include <hip/hip_bf16.h>
#include <math.h>

#define NN   20000
#define NE   320000
#define TT   24
#define SDIM 16
#define DDIM 8
#define HID  128
#define HEADS 4
#define DPH  32
#define NL   3
#define TC   2          // timesteps batched per GNN chunk

typedef unsigned short u16;
typedef unsigned int   u32;
typedef __attribute__((ext_vector_type(8))) short  short8;
typedef __attribute__((ext_vector_type(4))) float  floatx4;

__device__ __forceinline__ u16 f2bf(float x) {          // round-to-nearest-even
  u32 u = __float_as_uint(x);
  return (u16)((u + 0x7fff + ((u >> 16) & 1)) >> 16);
}
__device__ __forceinline__ float bf2f(u16 b) {
  return __uint_as_float(((u32)b) << 16);
}

// ---------------- CSR build (group edges by dst) ----------------
__global__ void k_count(const int* __restrict__ dst, int* __restrict__ cnt) {
  int e = blockIdx.x * 256 + threadIdx.x;
  if (e < NE) atomicAdd(&cnt[dst[e]], 1);
}

__global__ __launch_bounds__(1024) void k_scan(const int* __restrict__ cnt,
    int* __restrict__ rowptr, int* __restrict__ cursor) {
  __shared__ int sh[1024];
  int tid = threadIdx.x;
  const int CH = 20;                      // 1024*20 >= NN
  int base = tid * CH;
  int local[CH];
  int s = 0;
  #pragma unroll
  for (int i = 0; i < CH; i++) {
    int idx = base + i;
    int v = (idx < NN) ? cnt[idx] : 0;
    local[i] = s;
    s += v;
  }
  sh[tid] = s;
  __syncthreads();
  for (int off = 1; off < 1024; off <<= 1) {
    int tv = (tid >= off) ? sh[tid - off] : 0;
    __syncthreads();
    sh[tid] += tv;
    __syncthreads();
  }
  int pre = (tid > 0) ? sh[tid - 1] : 0;
  #pragma unroll
  for (int i = 0; i < CH; i++) {
    int idx = base + i;
    if (idx < NN) { int e = pre + local[i]; rowptr[idx] = e; cursor[idx] = e; }
  }
  if (tid == 1023) rowptr[NN] = sh[1023];
}

__global__ void k_fill(const int* __restrict__ src, const int* __restrict__ dst,
    int* __restrict__ cursor, int* __restrict__ col) {
  int e = blockIdx.x * 256 + threadIdx.x;
  if (e < NE) {
    int pos = atomicAdd(&cursor[dst[e]], 1);
    col[pos] = src[e];
  }
}

// ---------------- weight prep ----------------
// LSTM weights, GATE-INTERLEAVED: Bt[4c+g][k] = W[g*128+c][k], W = [Wih | Whh]
__global__ void k_prepw_lstm(const float* __restrict__ Wih, const float* __restrict__ Whh,
    u16* __restrict__ Bt) {
  int idx = blockIdx.x * 256 + threadIdx.x;
  if (idx < 512 * 256) {
    int jp = idx >> 8, k = idx & 255;
    int c = jp >> 2, g = jp & 3;
    int j = g * 128 + c;
    float v = (k < 128) ? Wih[(size_t)j * 128 + k] : Whh[(size_t)j * 128 + (k - 128)];
    Bt[idx] = f2bf(v);
  }
}
// combined bias, gate-interleaved: bs[4c+g] = bih[g*128+c] + bhh[g*128+c]; 2 cells
__global__ void k_prepb(const float* __restrict__ bih0, const float* __restrict__ bhh0,
    const float* __restrict__ bih1, const float* __restrict__ bhh1,
    float* __restrict__ bs01) {
  int t = threadIdx.x;               // 512 per block, blockIdx.x = cell
  const float* bih = blockIdx.x ? bih1 : bih0;
  const float* bhh = blockIdx.x ? bhh1 : bhh0;
  int c = t >> 2, g = t & 3;
  bs01[blockIdx.x * 512 + t] = bih[g * 128 + c] + bhh[g * 128 + c];
}
// GAT: Btg[l][n][k] = gatW[l][k][n]
__global__ void k_prepw_gat(const float* __restrict__ gatW, u16* __restrict__ Btg) {
  int idx = blockIdx.x * 256 + threadIdx.x;
  if (idx < NL * 128 * 128) {
    int l = idx >> 14, r = idx & 16383;
    int n = r >> 7, k = r & 127;
    Btg[idx] = f2bf(gatW[(size_t)l * 16384 + k * 128 + n]);
  }
}

// ---------------- input projection (TC timesteps): h[tc*N+n,:] = [xs[n]|xd[t0+tc,n]] @ W + b ----
__global__ __launch_bounds__(256) void k_proj(const float* __restrict__ xs,
    const float* __restrict__ xdt, const float* __restrict__ W,
    const float* __restrict__ b, float* __restrict__ h, u16* __restrict__ hbf) {
  __shared__ float Ws[24 * HID];
  __shared__ float xin[16][24];
  int tid = threadIdx.x;
  int tc = blockIdx.y;
  for (int i = tid; i < 24 * HID; i += 256) Ws[i] = W[i];
  int n0 = blockIdx.x * 16;
  for (int i = tid; i < 16 * 24; i += 256) {
    int r = i / 24, c = i % 24;
    int n = n0 + r;
    xin[r][c] = (c < SDIM) ? xs[(size_t)n * SDIM + c]
                           : xdt[(size_t)tc * NN * DDIM + (size_t)n * DDIM + (c - SDIM)];
  }
  __syncthreads();
  int ch = tid & 127, rb = (tid >> 7) * 8;
  for (int r = rb; r < rb + 8; r++) {
    float acc = b[ch];
    #pragma unroll
    for (int k = 0; k < 24; k++) acc = fmaf(xin[r][k], Ws[k * HID + ch], acc);
    size_t o = ((size_t)tc * NN + n0 + r) * HID + ch;
    h[o] = acc;
    hbf[o] = f2bf(acc);
  }
}

#define TBM 128
#define TBN 64
#define TBK 64

// ---------------- GAT GEMM + fused attention-logit epilogue ----------------
// xpbf[M,128] (bf16) = A[M,128] @ Bt^T ; asrc/adst[row,h] = dot(xp_row[h*32:+32], att)
__global__ __launch_bounds__(256) void k_bgemm_gat(const u16* __restrict__ A,
    const u16* __restrict__ Bt, const float* __restrict__ as_,
    const float* __restrict__ ad_, u16* __restrict__ xpbf,
    float* __restrict__ asrc, float* __restrict__ adst, int M) {
  __shared__ u16 As[TBM][TBK + 8];
  __shared__ u16 Bs[TBN][TBK + 8];
  int tid = threadIdx.x;
  int wid = tid >> 6, lane = tid & 63;
  int wr = wid >> 1, wc = wid & 1;
  int lrow = lane & 15, lgrp = lane >> 4;
  int row0 = blockIdx.x * TBM, col0 = blockIdx.y * TBN;
  floatx4 acc[4][2] = {};
  for (int k0 = 0; k0 < 128; k0 += TBK) {
    #pragma unroll
    for (int i = 0; i < 4; i++) {
      int idx = tid + i * 256;
      int r = idx >> 3, g = idx & 7;
      int gr = row0 + r;
      short8 v = {};
      if (gr < M) v = *(const short8*)(A + (size_t)gr * 128 + k0 + g * 8);
      *(short8*)&As[r][g * 8] = v;
    }
    #pragma unroll
    for (int i = 0; i < 2; i++) {
      int idx = tid + i * 256;
      int r = idx >> 3, g = idx & 7;
      *(short8*)&Bs[r][g * 8] = *(const short8*)(Bt + (size_t)(col0 + r) * 128 + k0 + g * 8);
    }
    __syncthreads();
    #pragma unroll
    for (int kk = 0; kk < TBK; kk += 32) {
      short8 bfr[2];
      #pragma unroll
      for (int n = 0; n < 2; n++)
        bfr[n] = *(const short8*)&Bs[wc * 32 + n * 16 + lrow][kk + lgrp * 8];
      #pragma unroll
      for (int m = 0; m < 4; m++) {
        short8 af = *(const short8*)&As[wr * 64 + m * 16 + lrow][kk + lgrp * 8];
        acc[m][0] = __builtin_amdgcn_mfma_f32_16x16x32_bf16(af, bfr[0], acc[m][0], 0, 0, 0);
        acc[m][1] = __builtin_amdgcn_mfma_f32_16x16x32_bf16(af, bfr[1], acc[m][1], 0, 0, 0);
      }
    }
    __syncthreads();
  }
  // epilogue: bf16 xp write + attn logits (wave's 32-col slab = one head)
  int head = (col0 >> 5) + wc;
  float as0 = as_[head * 32 + lrow], as1 = as_[head * 32 + 16 + lrow];
  float ad0 = ad_[head * 32 + lrow], ad1 = ad_[head * 32 + 16 + lrow];
  #pragma unroll
  for (int m = 0; m < 4; m++) {
    #pragma unroll
    for (int r = 0; r < 4; r++) {
      int grow = row0 + wr * 64 + m * 16 + lgrp * 4 + r;
      float v0 = acc[m][0][r], v1 = acc[m][1][r];
      if (grow < M) {
        xpbf[(size_t)grow * HID + col0 + wc * 32 + lrow]      = f2bf(v0);
        xpbf[(size_t)grow * HID + col0 + wc * 32 + 16 + lrow] = f2bf(v1);
      }
      float ps = v0 * as0 + v1 * as1;
      float pd = v0 * ad0 + v1 * ad1;
      #pragma unroll
      for (int off = 1; off < 16; off <<= 1) {
        ps += __shfl_xor(ps, off);
        pd += __shfl_xor(pd, off);
      }
      if (lrow == 0 && grow < M) {
        asrc[grow * HEADS + head] = ps;
        adst[grow * HEADS + head] = pd;
      }
    }
  }
}

// ---------------- GAT aggregation + residual + LayerNorm + ReLU (TC-batched) ----------------
__global__ __launch_bounds__(256) void k_aggr(const u16* __restrict__ xpbf,
    float* __restrict__ h, u16* __restrict__ hbf, const float* __restrict__ asrc,
    const float* __restrict__ adst, const int* __restrict__ rowptr,
    const int* __restrict__ col, const float* __restrict__ bias,
    const float* __restrict__ lng, const float* __restrict__ lnb) {
  int wid = threadIdx.x >> 6, lane = threadIdx.x & 63;
  int n = blockIdx.x * 4 + wid;                    // 0 .. TC*NN
  int node = n, base = 0;
  if (n >= NN) { node = n - NN; base = NN; }
  int hh = lane >> 4;
  float ad = adst[n * HEADS + hh];
  float e0 = asrc[n * HEADS + hh] + ad;            // self-loop
  e0 = (e0 > 0.f) ? e0 : 0.2f * e0;
  float m = e0, den = 1.f;
  u32 xv = ((const u32*)(xpbf + (size_t)n * HID))[lane];
  float mg0 = bf2f((u16)(xv & 0xffff)), mg1 = bf2f((u16)(xv >> 16));
  int rs = rowptr[node], re = rowptr[node + 1];
  int j = rs;
  for (; j + 1 < re; j += 2) {                     // 2-edge unrolled online softmax
    int r0 = base + col[j], r1 = base + col[j + 1];
    float ev0 = asrc[r0 * HEADS + hh] + ad;
    float ev1 = asrc[r1 * HEADS + hh] + ad;
    ev0 = (ev0 > 0.f) ? ev0 : 0.2f * ev0;
    ev1 = (ev1 > 0.f) ? ev1 : 0.2f * ev1;
    u32 x0 = ((const u32*)(xpbf + (size_t)r0 * HID))[lane];
    u32 x1 = ((const u32*)(xpbf + (size_t)r1 * HID))[lane];
    float mn = fmaxf(m, fmaxf(ev0, ev1));
    float sc = __expf(m - mn);
    float w0 = __expf(ev0 - mn);
    float w1 = __expf(ev1 - mn);
    den = den * sc + w0 + w1;
    mg0 = mg0 * sc + w0 * bf2f((u16)(x0 & 0xffff)) + w1 * bf2f((u16)(x1 & 0xffff));
    mg1 = mg1 * sc + w0 * bf2f((u16)(x0 >> 16))    + w1 * bf2f((u16)(x1 >> 16));
    m = mn;
  }
  if (j < re) {
    int r0 = base + col[j];
    float ev = asrc[r0 * HEADS + hh] + ad;
    ev = (ev > 0.f) ? ev : 0.2f * ev;
    u32 x2 = ((const u32*)(xpbf + (size_t)r0 * HID))[lane];
    float mn = fmaxf(m, ev);
    float sc = __expf(m - mn);
    float w  = __expf(ev - mn);
    den = den * sc + w;
    mg0 = mg0 * sc + w * bf2f((u16)(x2 & 0xffff));
    mg1 = mg1 * sc + w * bf2f((u16)(x2 >> 16));
    m = mn;
  }
  float inv = 1.f / (den + 1e-16f);
  int c0 = lane * 2;
  size_t hoff = (size_t)n * HID + c0;
  float o0 = mg0 * inv + bias[c0]     + h[hoff];
  float o1 = mg1 * inv + bias[c0 + 1] + h[hoff + 1];
  float s2 = o0 + o1;
  #pragma unroll
  for (int off = 32; off; off >>= 1) s2 += __shfl_xor(s2, off);
  float mu = s2 * (1.f / HID);
  float d0 = o0 - mu, d1 = o1 - mu;
  float v2 = d0 * d0 + d1 * d1;
  #pragma unroll
  for (int off = 32; off; off >>= 1) v2 += __shfl_xor(v2, off);
  float rstd = rsqrtf(v2 * (1.f / HID) + 1e-5f);
  o0 = lng[c0] * d0 * rstd + lnb[c0];
  o1 = lng[c0 + 1] * d1 * rstd + lnb[c0 + 1];
  o0 = fmaxf(o0, 0.f);
  o1 = fmaxf(o1, 0.f);
  h[hoff]     = o0;
  h[hoff + 1] = o1;
  *(u32*)(hbf + hoff) = (u32)f2bf(o0) | ((u32)f2bf(o1) << 16);
}

// ---------------- LSTM GEMM + fused gate epilogue ----------------
__global__ __launch_bounds__(256) void k_bgemm_lstm(const u16* __restrict__ A0,
    const u16* __restrict__ A1, const u16* __restrict__ Bt,
    const float* __restrict__ bs, float* __restrict__ cst,
    u16* __restrict__ hout, int M) {
  __shared__ __align__(16) char smem[34816];   // max(As+Bs=27648, zs=128*68*4=34816)
  u16 (*As)[TBK + 8] = (u16(*)[TBK + 8])smem;
  u16 (*Bs)[TBK + 8] = (u16(*)[TBK + 8])(smem + TBM * (TBK + 8) * 2);
  float (*zs)[68] = (float(*)[68])smem;
  int tid = threadIdx.x;
  int wid = tid >> 6, lane = tid & 63;
  int wr = wid >> 1, wc = wid & 1;
  int lrow = lane & 15, lgrp = lane >> 4;
  int row0 = blockIdx.x * TBM, col0 = blockIdx.y * TBN;
  floatx4 acc[4][2] = {};
  for (int k0 = 0; k0 < 256; k0 += TBK) {
    const u16* Ap = (k0 < 128) ? A0 : A1;
    int kb = k0 & 127;
    #pragma unroll
    for (int i = 0; i < 4; i++) {
      int idx = tid + i * 256;
      int r = idx >> 3, g = idx & 7;
      int gr = row0 + r;
      short8 v = {};
      if (gr < M) v = *(const short8*)(Ap + (size_t)gr * 128 + kb + g * 8);
      *(short8*)&As[r][g * 8] = v;
    }
    #pragma unroll
    for (int i = 0; i < 2; i++) {
      int idx = tid + i * 256;
      int r = idx >> 3, g = idx & 7;
      *(short8*)&Bs[r][g * 8] = *(const short8*)(Bt + (size_t)(col0 + r) * 256 + k0 + g * 8);
    }
    __syncthreads();
    #pragma unroll
    for (int kk = 0; kk < TBK; kk += 32) {
      short8 bfr[2];
      #pragma unroll
      for (int n = 0; n < 2; n++)
        bfr[n] = *(const short8*)&Bs[wc * 32 + n * 16 + lrow][kk + lgrp * 8];
      #pragma unroll
      for (int m = 0; m < 4; m++) {
        short8 af = *(const short8*)&As[wr * 64 + m * 16 + lrow][kk + lgrp * 8];
        acc[m][0] = __builtin_amdgcn_mfma_f32_16x16x32_bf16(af, bfr[0], acc[m][0], 0, 0, 0);
        acc[m][1] = __builtin_amdgcn_mfma_f32_16x16x32_bf16(af, bfr[1], acc[m][1], 0, 0, 0);
      }
    }
    __syncthreads();
  }
  // stage z-tile to LDS
  #pragma unroll
  for (int m = 0; m < 4; m++)
    #pragma unroll
    for (int n = 0; n < 2; n++)
      #pragma unroll
      for (int r = 0; r < 4; r++)
        zs[wr * 64 + m * 16 + lgrp * 4 + r][wc * 32 + n * 16 + lrow] = acc[m][n][r];
  __syncthreads();
  // gate epilogue: 128 rows x 16 channels per block
  int ch0 = blockIdx.y * 16;
  #pragma unroll
  for (int it = 0; it < 8; it++) {
    int o = tid + it * 256;
    int r = o >> 4, lc = o & 15;
    int grow = row0 + r;
    if (grow < M) {
      float4 zi = *(float4*)&zs[r][lc * 4];
      int ch = ch0 + lc;
      size_t gi = (size_t)grow * HID + ch;
      float ii = zi.x + bs[4 * ch + 0];
      float ff = zi.y + bs[4 * ch + 1];
      float gg = zi.z + bs[4 * ch + 2];
      float oo = zi.w + bs[4 * ch + 3];
      float si = 1.f / (1.f + __expf(-ii));
      float sf = 1.f / (1.f + __expf(-ff));
      float so = 1.f / (1.f + __expf(-oo));
      float tg = tanhf(gg);
      float cn = sf * cst[gi] + si * tg;
      cst[gi] = cn;
      hout[gi] = f2bf(so * tanhf(cn));
    }
  }
}

// ---------------- output MLP: relu(h1@W1+b1)@W2+b2 ----------------
__global__ __launch_bounds__(64) void k_mlp(const u16* __restrict__ h1,
    const float* __restrict__ W1, const float* __restrict__ b1,
    const float* __restrict__ W2, const float* __restrict__ b2,
    float* __restrict__ out) {
  int n = blockIdx.x, j = threadIdx.x;
  const u16* hr = h1 + (size_t)n * HID;
  float acc = b1[j];
  #pragma unroll 8
  for (int k = 0; k < HID; k++) acc = fmaf(bf2f(hr[k]), W1[(size_t)k * 64 + j], acc);
  acc = fmaxf(acc, 0.f);
  float p = acc * W2[j];
  #pragma unroll
  for (int off = 32; off; off >>= 1) p += __shfl_xor(p, off);
  if (j == 0) out[n] = p + b2[0];
}

extern "C" void kernel_launch(void* const* d_in, const int* in_sizes, int n_in,
                              void* d_out, int out_size, void* d_ws, size_t ws_size,
                              hipStream_t stream) {
  const float* xs    = (const float*)d_in[0];
  const float* xd    = (const float*)d_in[1];
  const int*   ei    = (const int*)d_in[2];
  const float* projW = (const float*)d_in[3];
  const float* projb = (const float*)d_in[4];
  const float* gatW  = (const float*)d_in[5];
  const float* attS  = (const float*)d_in[6];
  const float* attD  = (const float*)d_in[7];
  const float* gatb  = (const float*)d_in[8];
  const float* lng   = (const float*)d_in[9];
  const float* lnb   = (const float*)d_in[10];
  const float* Wih0  = (const float*)d_in[11];
  const float* Whh0  = (const float*)d_in[12];
  const float* bih0  = (const float*)d_in[13];
  const float* bhh0  = (const float*)d_in[14];
  const float* Wih1  = (const float*)d_in[15];
  const float* Whh1  = (const float*)d_in[16];
  const float* bih1  = (const float*)d_in[17];
  const float* bhh1  = (const float*)d_in[18];
  const float* oW1   = (const float*)d_in[19];
  const float* ob1   = (const float*)d_in[20];
  const float* oW2   = (const float*)d_in[21];
  const float* ob2   = (const float*)d_in[22];
  float* out = (float*)d_out;

  // -------- workspace layout (~86 MB) --------
  char* w = (char*)d_ws;
  size_t off = 0;
  auto alloc = [&](size_t bytes) { void* p = w + off; off += (bytes + 255) & ~(size_t)255; return p; };
  float* hcur  = (float*)alloc((size_t)TC * NN * HID * 4);   // fp32 h, TC timesteps
  u16*   hbf   = (u16*)  alloc((size_t)TC * NN * HID * 2);   // bf16 mirror
  u16*   xpbf  = (u16*)  alloc((size_t)TC * NN * HID * 2);   // bf16 xp
  float* asrc  = (float*)alloc((size_t)TC * NN * HEADS * 4);
  float* adst  = (float*)alloc((size_t)TC * NN * HEADS * 4);
  float* c01   = (float*)alloc((size_t)2 * NN * HID * 4);    // c0,c1
  float* c0 = c01, *c1 = c01 + (size_t)NN * HID;
  u16*   h0p   = (u16*)  alloc((size_t)2 * NN * HID * 2);    // h0 ping-pong
  u16*   h1p   = (u16*)  alloc((size_t)2 * NN * HID * 2);    // h1 ping-pong
  u16*   h0buf[2] = { h0p, h0p + (size_t)NN * HID };
  u16*   h1buf[2] = { h1p, h1p + (size_t)NN * HID };
  u16*   Wc0bf = (u16*)alloc((size_t)512 * 256 * 2);
  u16*   Wc1bf = (u16*)alloc((size_t)512 * 256 * 2);
  float* bs01  = (float*)alloc((size_t)1024 * 4);
  float* bs0 = bs01, *bs1 = bs01 + 512;
  u16*   gatWbf= (u16*)alloc((size_t)NL * 128 * 128 * 2);
  int* cnt    = (int*)alloc((size_t)NN * 4);
  int* rowptr = (int*)alloc((size_t)(NN + 1) * 4);
  int* cursor = (int*)alloc((size_t)NN * 4);
  int* col    = (int*)alloc((size_t)NE * 4);

  const int* esrc = ei;
  const int* edst = ei + NE;

  // -------- CSR (edge_index identical across t and layers) --------
  hipMemsetAsync(cnt, 0, (size_t)NN * 4, stream);
  k_count<<<(NE + 255) / 256, 256, 0, stream>>>(edst, cnt);
  k_scan<<<1, 1024, 0, stream>>>(cnt, rowptr, cursor);
  k_fill<<<(NE + 255) / 256, 256, 0, stream>>>(esrc, edst, cursor, col);

  // -------- weight/bias prep + state init --------
  k_prepw_lstm<<<(512 * 256) / 256, 256, 0, stream>>>(Wih0, Whh0, Wc0bf);
  k_prepw_lstm<<<(512 * 256) / 256, 256, 0, stream>>>(Wih1, Whh1, Wc1bf);
  k_prepb<<<2, 512, 0, stream>>>(bih0, bhh0, bih1, bhh1, bs01);
  k_prepw_gat<<<(NL * 128 * 128) / 256, 256, 0, stream>>>(gatW, gatWbf);
  hipMemsetAsync(c01, 0, (size_t)2 * NN * HID * 4, stream);
  hipMemsetAsync(h0buf[0], 0, (size_t)NN * HID * 2, stream);
  hipMemsetAsync(h1buf[0], 0, (size_t)NN * HID * 2, stream);

  // -------- per chunk: batched GNN (TC timesteps), then sequential LSTM --------
  const int gx  = (NN + TBM - 1) / TBM;             // 157
  const int gx2 = (TC * NN + TBM - 1) / TBM;        // 313
  for (int tcb = 0; tcb < TT / TC; tcb++) {
    k_proj<<<dim3(NN / 16, TC), 256, 0, stream>>>(
        xs, xd + (size_t)(tcb * TC) * NN * DDIM, projW, projb, hcur, hbf);
    for (int l = 0; l < NL; l++) {
      k_bgemm_gat<<<dim3(gx2, 2), 256, 0, stream>>>(
          hbf, gatWbf + (size_t)l * 128 * 128,
          attS + l * HEADS * DPH, attD + l * HEADS * DPH,
          xpbf, asrc, adst, TC * NN);
      k_aggr<<<TC * NN / 4, 256, 0, stream>>>(
          xpbf, hcur, hbf, asrc, adst, rowptr, col, gatb + (size_t)l * HID,
          lng + (size_t)l * HID, lnb + (size_t)l * HID);
    }
    for (int s2 = 0; s2 < TC; s2++) {
      int t = tcb * TC + s2;
      int pi = t & 1;
      k_bgemm_lstm<<<dim3(gx, 8), 256, 0, stream>>>(
          hbf + (size_t)s2 * NN * HID, h0buf[pi], Wc0bf, bs0, c0, h0buf[pi ^ 1], NN);
      k_bgemm_lstm<<<dim3(gx, 8), 256, 0, stream>>>(
          h0buf[pi ^ 1], h1buf[pi], Wc1bf, bs1, c1, h1buf[pi ^ 1], NN);
    }
  }

  // TT even -> final h1 lives in h1buf[0]
  k_mlp<<<NN, 64, 0, stream>>>(h1buf[0], oW1, ob1, oW2, ob2, out);
}

// Round 8
// 3799.445 us; speedup vs baseline: 2.9947x; 1.0930x over previous
//
#include <hip/hip_runtime.h>
#include <hip/hip_bf16.h>
#include <math.h>

#define NN   20000
#define NE   320000
#define TT   24
#define SDIM 16
#define DDIM 8
#define HID  128
#define HEADS 4
#define DPH  32
#define NL   3
#define TC   2          // timesteps batched per GNN chunk

typedef unsigned short u16;
typedef unsigned int   u32;
typedef __attribute__((ext_vector_type(8))) short  short8;
typedef __attribute__((ext_vector_type(4))) float  floatx4;

__device__ __forceinline__ u16 f2bf(float x) {          // round-to-nearest-even
  u32 u = __float_as_uint(x);
  return (u16)((u + 0x7fff + ((u >> 16) & 1)) >> 16);
}
__device__ __forceinline__ float bf2f(u16 b) {
  return __uint_as_float(((u32)b) << 16);
}

// ---------------- CSR build (group edges by dst) ----------------
__global__ void k_count(const int* __restrict__ dst, int* __restrict__ cnt) {
  int e = blockIdx.x * 256 + threadIdx.x;
  if (e < NE) atomicAdd(&cnt[dst[e]], 1);
}

__global__ __launch_bounds__(1024) void k_scan(const int* __restrict__ cnt,
    int* __restrict__ rowptr, int* __restrict__ cursor) {
  __shared__ int sh[1024];
  int tid = threadIdx.x;
  const int CH = 20;                      // 1024*20 >= NN
  int base = tid * CH;
  int local[CH];
  int s = 0;
  #pragma unroll
  for (int i = 0; i < CH; i++) {
    int idx = base + i;
    int v = (idx < NN) ? cnt[idx] : 0;
    local[i] = s;
    s += v;
  }
  sh[tid] = s;
  __syncthreads();
  for (int off = 1; off < 1024; off <<= 1) {
    int tv = (tid >= off) ? sh[tid - off] : 0;
    __syncthreads();
    sh[tid] += tv;
    __syncthreads();
  }
  int pre = (tid > 0) ? sh[tid - 1] : 0;
  #pragma unroll
  for (int i = 0; i < CH; i++) {
    int idx = base + i;
    if (idx < NN) { int e = pre + local[i]; rowptr[idx] = e; cursor[idx] = e; }
  }
  if (tid == 1023) rowptr[NN] = sh[1023];
}

__global__ void k_fill(const int* __restrict__ src, const int* __restrict__ dst,
    int* __restrict__ cursor, int* __restrict__ col) {
  int e = blockIdx.x * 256 + threadIdx.x;
  if (e < NE) {
    int pos = atomicAdd(&cursor[dst[e]], 1);
    col[pos] = src[e];
  }
}

// ---------------- weight prep ----------------
// LSTM weights, GATE-INTERLEAVED: Bt[4c+g][k] = W[g*128+c][k], W = [Wih | Whh]
__global__ void k_prepw_lstm(const float* __restrict__ Wih, const float* __restrict__ Whh,
    u16* __restrict__ Bt) {
  int idx = blockIdx.x * 256 + threadIdx.x;
  if (idx < 512 * 256) {
    int jp = idx >> 8, k = idx & 255;
    int c = jp >> 2, g = jp & 3;
    int j = g * 128 + c;
    float v = (k < 128) ? Wih[(size_t)j * 128 + k] : Whh[(size_t)j * 128 + (k - 128)];
    Bt[idx] = f2bf(v);
  }
}
// combined bias, gate-interleaved: bs[4c+g] = bih[g*128+c] + bhh[g*128+c]; 2 cells
__global__ void k_prepb(const float* __restrict__ bih0, const float* __restrict__ bhh0,
    const float* __restrict__ bih1, const float* __restrict__ bhh1,
    float* __restrict__ bs01) {
  int t = threadIdx.x;               // 512 per block, blockIdx.x = cell
  const float* bih = blockIdx.x ? bih1 : bih0;
  const float* bhh = blockIdx.x ? bhh1 : bhh0;
  int c = t >> 2, g = t & 3;
  bs01[blockIdx.x * 512 + t] = bih[g * 128 + c] + bhh[g * 128 + c];
}
// GAT: Btg[l][n][k] = gatW[l][k][n]
__global__ void k_prepw_gat(const float* __restrict__ gatW, u16* __restrict__ Btg) {
  int idx = blockIdx.x * 256 + threadIdx.x;
  if (idx < NL * 128 * 128) {
    int l = idx >> 14, r = idx & 16383;
    int n = r >> 7, k = r & 127;
    Btg[idx] = f2bf(gatW[(size_t)l * 16384 + k * 128 + n]);
  }
}

// ---------------- input projection (TC timesteps): hbf[tc*N+n,:] = [xs[n]|xd[t0+tc,n]] @ W + b ----
__global__ __launch_bounds__(256) void k_proj(const float* __restrict__ xs,
    const float* __restrict__ xdt, const float* __restrict__ W,
    const float* __restrict__ b, u16* __restrict__ hbf) {
  __shared__ float Ws[24 * HID];
  __shared__ float xin[16][24];
  int tid = threadIdx.x;
  int tc = blockIdx.y;
  for (int i = tid; i < 24 * HID; i += 256) Ws[i] = W[i];
  int n0 = blockIdx.x * 16;
  for (int i = tid; i < 16 * 24; i += 256) {
    int r = i / 24, c = i % 24;
    int n = n0 + r;
    xin[r][c] = (c < SDIM) ? xs[(size_t)n * SDIM + c]
                           : xdt[(size_t)tc * NN * DDIM + (size_t)n * DDIM + (c - SDIM)];
  }
  __syncthreads();
  int ch = tid & 127, rb = (tid >> 7) * 8;
  for (int r = rb; r < rb + 8; r++) {
    float acc = b[ch];
    #pragma unroll
    for (int k = 0; k < 24; k++) acc = fmaf(xin[r][k], Ws[k * HID + ch], acc);
    hbf[((size_t)tc * NN + n0 + r) * HID + ch] = f2bf(acc);
  }
}

#define TBM 128
#define TBN 64
#define TBK 64

// ---------------- GAT GEMM + fused attention-logit epilogue ----------------
// xpbf[M,128] (bf16) = A[M,128] @ Bt^T ; asrc/adst[row,h] = dot(xp_row[h*32:+32], att)
__global__ __launch_bounds__(256) void k_bgemm_gat(const u16* __restrict__ A,
    const u16* __restrict__ Bt, const float* __restrict__ as_,
    const float* __restrict__ ad_, u16* __restrict__ xpbf,
    float* __restrict__ asrc, float* __restrict__ adst, int M) {
  __shared__ u16 As[TBM][TBK + 8];
  __shared__ u16 Bs[TBN][TBK + 8];
  int tid = threadIdx.x;
  int wid = tid >> 6, lane = tid & 63;
  int wr = wid >> 1, wc = wid & 1;
  int lrow = lane & 15, lgrp = lane >> 4;
  int row0 = blockIdx.x * TBM, col0 = blockIdx.y * TBN;
  floatx4 acc[4][2] = {};
  for (int k0 = 0; k0 < 128; k0 += TBK) {
    #pragma unroll
    for (int i = 0; i < 4; i++) {
      int idx = tid + i * 256;
      int r = idx >> 3, g = idx & 7;
      int gr = row0 + r;
      short8 v = {};
      if (gr < M) v = *(const short8*)(A + (size_t)gr * 128 + k0 + g * 8);
      *(short8*)&As[r][g * 8] = v;
    }
    #pragma unroll
    for (int i = 0; i < 2; i++) {
      int idx = tid + i * 256;
      int r = idx >> 3, g = idx & 7;
      *(short8*)&Bs[r][g * 8] = *(const short8*)(Bt + (size_t)(col0 + r) * 128 + k0 + g * 8);
    }
    __syncthreads();
    #pragma unroll
    for (int kk = 0; kk < TBK; kk += 32) {
      short8 bfr[2];
      #pragma unroll
      for (int n = 0; n < 2; n++)
        bfr[n] = *(const short8*)&Bs[wc * 32 + n * 16 + lrow][kk + lgrp * 8];
      #pragma unroll
      for (int m = 0; m < 4; m++) {
        short8 af = *(const short8*)&As[wr * 64 + m * 16 + lrow][kk + lgrp * 8];
        acc[m][0] = __builtin_amdgcn_mfma_f32_16x16x32_bf16(af, bfr[0], acc[m][0], 0, 0, 0);
        acc[m][1] = __builtin_amdgcn_mfma_f32_16x16x32_bf16(af, bfr[1], acc[m][1], 0, 0, 0);
      }
    }
    __syncthreads();
  }
  // epilogue: bf16 xp write + attn logits (wave's 32-col slab = one head)
  int head = (col0 >> 5) + wc;
  float as0 = as_[head * 32 + lrow], as1 = as_[head * 32 + 16 + lrow];
  float ad0 = ad_[head * 32 + lrow], ad1 = ad_[head * 32 + 16 + lrow];
  #pragma unroll
  for (int m = 0; m < 4; m++) {
    #pragma unroll
    for (int r = 0; r < 4; r++) {
      int grow = row0 + wr * 64 + m * 16 + lgrp * 4 + r;
      float v0 = acc[m][0][r], v1 = acc[m][1][r];
      if (grow < M) {
        xpbf[(size_t)grow * HID + col0 + wc * 32 + lrow]      = f2bf(v0);
        xpbf[(size_t)grow * HID + col0 + wc * 32 + 16 + lrow] = f2bf(v1);
      }
      float ps = v0 * as0 + v1 * as1;
      float pd = v0 * ad0 + v1 * ad1;
      #pragma unroll
      for (int off = 1; off < 16; off <<= 1) {
        ps += __shfl_xor(ps, off);
        pd += __shfl_xor(pd, off);
      }
      if (lrow == 0 && grow < M) {
        asrc[grow * HEADS + head] = ps;
        adst[grow * HEADS + head] = pd;
      }
    }
  }
}

// ---------------- GAT aggregation + residual + LayerNorm + ReLU (TC-batched) ----------------
// all-bf16 residual path; 4-edge unrolled online softmax
__global__ __launch_bounds__(256) void k_aggr(const u16* __restrict__ xpbf,
    u16* __restrict__ hbf, const float* __restrict__ asrc,
    const float* __restrict__ adst, const int* __restrict__ rowptr,
    const int* __restrict__ col, const float* __restrict__ bias,
    const float* __restrict__ lng, const float* __restrict__ lnb) {
  int wid = threadIdx.x >> 6, lane = threadIdx.x & 63;
  int n = blockIdx.x * 4 + wid;                    // 0 .. TC*NN
  int node = n, base = 0;
  if (n >= NN) { node = n - NN; base = NN; }
  int hh = lane >> 4;
  float ad = adst[n * HEADS + hh];
  float e0 = asrc[n * HEADS + hh] + ad;            // self-loop
  e0 = (e0 > 0.f) ? e0 : 0.2f * e0;
  float m = e0, den = 1.f;
  u32 xv = ((const u32*)(xpbf + (size_t)n * HID))[lane];
  float mg0 = bf2f((u16)(xv & 0xffff)), mg1 = bf2f((u16)(xv >> 16));
  int rs = rowptr[node], re = rowptr[node + 1];
  int j = rs;
  for (; j + 4 <= re; j += 4) {                    // 4-edge unrolled online softmax
    int r0 = base + col[j],     r1 = base + col[j + 1];
    int r2 = base + col[j + 2], r3 = base + col[j + 3];
    float ev0 = asrc[r0 * HEADS + hh] + ad;
    float ev1 = asrc[r1 * HEADS + hh] + ad;
    float ev2 = asrc[r2 * HEADS + hh] + ad;
    float ev3 = asrc[r3 * HEADS + hh] + ad;
    u32 x0 = ((const u32*)(xpbf + (size_t)r0 * HID))[lane];
    u32 x1 = ((const u32*)(xpbf + (size_t)r1 * HID))[lane];
    u32 x2 = ((const u32*)(xpbf + (size_t)r2 * HID))[lane];
    u32 x3 = ((const u32*)(xpbf + (size_t)r3 * HID))[lane];
    ev0 = (ev0 > 0.f) ? ev0 : 0.2f * ev0;
    ev1 = (ev1 > 0.f) ? ev1 : 0.2f * ev1;
    ev2 = (ev2 > 0.f) ? ev2 : 0.2f * ev2;
    ev3 = (ev3 > 0.f) ? ev3 : 0.2f * ev3;
    float mn = fmaxf(fmaxf(m, fmaxf(ev0, ev1)), fmaxf(ev2, ev3));
    float sc = __expf(m - mn);
    float w0 = __expf(ev0 - mn);
    float w1 = __expf(ev1 - mn);
    float w2 = __expf(ev2 - mn);
    float w3 = __expf(ev3 - mn);
    den = den * sc + ((w0 + w1) + (w2 + w3));
    mg0 = mg0 * sc + w0 * bf2f((u16)(x0 & 0xffff)) + w1 * bf2f((u16)(x1 & 0xffff))
                   + w2 * bf2f((u16)(x2 & 0xffff)) + w3 * bf2f((u16)(x3 & 0xffff));
    mg1 = mg1 * sc + w0 * bf2f((u16)(x0 >> 16))    + w1 * bf2f((u16)(x1 >> 16))
                   + w2 * bf2f((u16)(x2 >> 16))    + w3 * bf2f((u16)(x3 >> 16));
    m = mn;
  }
  for (; j < re; j++) {
    int r0 = base + col[j];
    float ev = asrc[r0 * HEADS + hh] + ad;
    ev = (ev > 0.f) ? ev : 0.2f * ev;
    u32 x2 = ((const u32*)(xpbf + (size_t)r0 * HID))[lane];
    float mn = fmaxf(m, ev);
    float sc = __expf(m - mn);
    float w  = __expf(ev - mn);
    den = den * sc + w;
    mg0 = mg0 * sc + w * bf2f((u16)(x2 & 0xffff));
    mg1 = mg1 * sc + w * bf2f((u16)(x2 >> 16));
    m = mn;
  }
  float inv = 1.f / (den + 1e-16f);
  int c0 = lane * 2;
  size_t hoff = (size_t)n * HID + c0;
  u32 hv = *(const u32*)(hbf + hoff);              // bf16 residual
  float o0 = mg0 * inv + bias[c0]     + bf2f((u16)(hv & 0xffff));
  float o1 = mg1 * inv + bias[c0 + 1] + bf2f((u16)(hv >> 16));
  float s2 = o0 + o1;
  #pragma unroll
  for (int off = 32; off; off >>= 1) s2 += __shfl_xor(s2, off);
  float mu = s2 * (1.f / HID);
  float d0 = o0 - mu, d1 = o1 - mu;
  float v2 = d0 * d0 + d1 * d1;
  #pragma unroll
  for (int off = 32; off; off >>= 1) v2 += __shfl_xor(v2, off);
  float rstd = rsqrtf(v2 * (1.f / HID) + 1e-5f);
  o0 = lng[c0] * d0 * rstd + lnb[c0];
  o1 = lng[c0 + 1] * d1 * rstd + lnb[c0 + 1];
  o0 = fmaxf(o0, 0.f);
  o1 = fmaxf(o1, 0.f);
  *(u32*)(hbf + hoff) = (u32)f2bf(o0) | ((u32)f2bf(o1) << 16);
}

// ---------------- LSTM GEMM + fused gate epilogue ----------------
__global__ __launch_bounds__(256) void k_bgemm_lstm(const u16* __restrict__ A0,
    const u16* __restrict__ A1, const u16* __restrict__ Bt,
    const float* __restrict__ bs, float* __restrict__ cst,
    u16* __restrict__ hout, int M) {
  __shared__ __align__(16) char smem[34816];   // max(As+Bs=27648, zs=128*68*4=34816)
  u16 (*As)[TBK + 8] = (u16(*)[TBK + 8])smem;
  u16 (*Bs)[TBK + 8] = (u16(*)[TBK + 8])(smem + TBM * (TBK + 8) * 2);
  float (*zs)[68] = (float(*)[68])smem;
  int tid = threadIdx.x;
  int wid = tid >> 6, lane = tid & 63;
  int wr = wid >> 1, wc = wid & 1;
  int lrow = lane & 15, lgrp = lane >> 4;
  int row0 = blockIdx.x * TBM, col0 = blockIdx.y * TBN;
  floatx4 acc[4][2] = {};
  for (int k0 = 0; k0 < 256; k0 += TBK) {
    const u16* Ap = (k0 < 128) ? A0 : A1;
    int kb = k0 & 127;
    #pragma unroll
    for (int i = 0; i < 4; i++) {
      int idx = tid + i * 256;
      int r = idx >> 3, g = idx & 7;
      int gr = row0 + r;
      short8 v = {};
      if (gr < M) v = *(const short8*)(Ap + (size_t)gr * 128 + kb + g * 8);
      *(short8*)&As[r][g * 8] = v;
    }
    #pragma unroll
    for (int i = 0; i < 2; i++) {
      int idx = tid + i * 256;
      int r = idx >> 3, g = idx & 7;
      *(short8*)&Bs[r][g * 8] = *(const short8*)(Bt + (size_t)(col0 + r) * 256 + k0 + g * 8);
    }
    __syncthreads();
    #pragma unroll
    for (int kk = 0; kk < TBK; kk += 32) {
      short8 bfr[2];
      #pragma unroll
      for (int n = 0; n < 2; n++)
        bfr[n] = *(const short8*)&Bs[wc * 32 + n * 16 + lrow][kk + lgrp * 8];
      #pragma unroll
      for (int m = 0; m < 4; m++) {
        short8 af = *(const short8*)&As[wr * 64 + m * 16 + lrow][kk + lgrp * 8];
        acc[m][0] = __builtin_amdgcn_mfma_f32_16x16x32_bf16(af, bfr[0], acc[m][0], 0, 0, 0);
        acc[m][1] = __builtin_amdgcn_mfma_f32_16x16x32_bf16(af, bfr[1], acc[m][1], 0, 0, 0);
      }
    }
    __syncthreads();
  }
  // stage z-tile to LDS
  #pragma unroll
  for (int m = 0; m < 4; m++)
    #pragma unroll
    for (int n = 0; n < 2; n++)
      #pragma unroll
      for (int r = 0; r < 4; r++)
        zs[wr * 64 + m * 16 + lgrp * 4 + r][wc * 32 + n * 16 + lrow] = acc[m][n][r];
  __syncthreads();
  // gate epilogue: 128 rows x 16 channels per block
  int ch0 = blockIdx.y * 16;
  #pragma unroll
  for (int it = 0; it < 8; it++) {
    int o = tid + it * 256;
    int r = o >> 4, lc = o & 15;
    int grow = row0 + r;
    if (grow < M) {
      float4 zi = *(float4*)&zs[r][lc * 4];
      int ch = ch0 + lc;
      size_t gi = (size_t)grow * HID + ch;
      float ii = zi.x + bs[4 * ch + 0];
      float ff = zi.y + bs[4 * ch + 1];
      float gg = zi.z + bs[4 * ch + 2];
      float oo = zi.w + bs[4 * ch + 3];
      float si = 1.f / (1.f + __expf(-ii));
      float sf = 1.f / (1.f + __expf(-ff));
      float so = 1.f / (1.f + __expf(-oo));
      float tg = tanhf(gg);
      float cn = sf * cst[gi] + si * tg;
      cst[gi] = cn;
      hout[gi] = f2bf(so * tanhf(cn));
    }
  }
}

// ---------------- output MLP: relu(h1@W1+b1)@W2+b2 ----------------
__global__ __launch_bounds__(64) void k_mlp(const u16* __restrict__ h1,
    const float* __restrict__ W1, const float* __restrict__ b1,
    const float* __restrict__ W2, const float* __restrict__ b2,
    float* __restrict__ out) {
  int n = blockIdx.x, j = threadIdx.x;
  const u16* hr = h1 + (size_t)n * HID;
  float acc = b1[j];
  #pragma unroll 8
  for (int k = 0; k < HID; k++) acc = fmaf(bf2f(hr[k]), W1[(size_t)k * 64 + j], acc);
  acc = fmaxf(acc, 0.f);
  float p = acc * W2[j];
  #pragma unroll
  for (int off = 32; off; off >>= 1) p += __shfl_xor(p, off);
  if (j == 0) out[n] = p + b2[0];
}

extern "C" void kernel_launch(void* const* d_in, const int* in_sizes, int n_in,
                              void* d_out, int out_size, void* d_ws, size_t ws_size,
                              hipStream_t stream) {
  const float* xs    = (const float*)d_in[0];
  const float* xd    = (const float*)d_in[1];
  const int*   ei    = (const int*)d_in[2];
  const float* projW = (const float*)d_in[3];
  const float* projb = (const float*)d_in[4];
  const float* gatW  = (const float*)d_in[5];
  const float* attS  = (const float*)d_in[6];
  const float* attD  = (const float*)d_in[7];
  const float* gatb  = (const float*)d_in[8];
  const float* lng   = (const float*)d_in[9];
  const float* lnb   = (const float*)d_in[10];
  const float* Wih0  = (const float*)d_in[11];
  const float* Whh0  = (const float*)d_in[12];
  const float* bih0  = (const float*)d_in[13];
  const float* bhh0  = (const float*)d_in[14];
  const float* Wih1  = (const float*)d_in[15];
  const float* Whh1  = (const float*)d_in[16];
  const float* bih1  = (const float*)d_in[17];
  const float* bhh1  = (const float*)d_in[18];
  const float* oW1   = (const float*)d_in[19];
  const float* ob1   = (const float*)d_in[20];
  const float* oW2   = (const float*)d_in[21];
  const float* ob2   = (const float*)d_in[22];
  float* out = (float*)d_out;

  // -------- workspace layout (~56 MB) --------
  char* w = (char*)d_ws;
  size_t off = 0;
  auto alloc = [&](size_t bytes) { void* p = w + off; off += (bytes + 255) & ~(size_t)255; return p; };
  u16*   hbf   = (u16*)  alloc((size_t)TC * NN * HID * 2);   // bf16 h (GEMM A + residual)
  u16*   xpbf  = (u16*)  alloc((size_t)TC * NN * HID * 2);   // bf16 xp
  float* asrc  = (float*)alloc((size_t)TC * NN * HEADS * 4);
  float* adst  = (float*)alloc((size_t)TC * NN * HEADS * 4);
  float* c01   = (float*)alloc((size_t)2 * NN * HID * 4);    // c0,c1
  float* c0 = c01, *c1 = c01 + (size_t)NN * HID;
  u16*   h0p   = (u16*)  alloc((size_t)2 * NN * HID * 2);    // h0 ping-pong
  u16*   h1p   = (u16*)  alloc((size_t)2 * NN * HID * 2);    // h1 ping-pong
  u16*   h0buf[2] = { h0p, h0p + (size_t)NN * HID };
  u16*   h1buf[2] = { h1p, h1p + (size_t)NN * HID };
  u16*   Wc0bf = (u16*)alloc((size_t)512 * 256 * 2);
  u16*   Wc1bf = (u16*)alloc((size_t)512 * 256 * 2);
  float* bs01  = (float*)alloc((size_t)1024 * 4);
  float* bs0 = bs01, *bs1 = bs01 + 512;
  u16*   gatWbf= (u16*)alloc((size_t)NL * 128 * 128 * 2);
  int* cnt    = (int*)alloc((size_t)NN * 4);
  int* rowptr = (int*)alloc((size_t)(NN + 1) * 4);
  int* cursor = (int*)alloc((size_t)NN * 4);
  int* col    = (int*)alloc((size_t)NE * 4);

  const int* esrc = ei;
  const int* edst = ei + NE;

  // -------- CSR (edge_index identical across t and layers) --------
  hipMemsetAsync(cnt, 0, (size_t)NN * 4, stream);
  k_count<<<(NE + 255) / 256, 256, 0, stream>>>(edst, cnt);
  k_scan<<<1, 1024, 0, stream>>>(cnt, rowptr, cursor);
  k_fill<<<(NE + 255) / 256, 256, 0, stream>>>(esrc, edst, cursor, col);

  // -------- weight/bias prep + state init --------
  k_prepw_lstm<<<(512 * 256) / 256, 256, 0, stream>>>(Wih0, Whh0, Wc0bf);
  k_prepw_lstm<<<(512 * 256) / 256, 256, 0, stream>>>(Wih1, Whh1, Wc1bf);
  k_prepb<<<2, 512, 0, stream>>>(bih0, bhh0, bih1, bhh1, bs01);
  k_prepw_gat<<<(NL * 128 * 128) / 256, 256, 0, stream>>>(gatW, gatWbf);
  hipMemsetAsync(c01, 0, (size_t)2 * NN * HID * 4, stream);
  hipMemsetAsync(h0buf[0], 0, (size_t)NN * HID * 2, stream);
  hipMemsetAsync(h1buf[0], 0, (size_t)NN * HID * 2, stream);

  // -------- per chunk: batched GNN (TC timesteps), then sequential LSTM --------
  const int gx  = (NN + TBM - 1) / TBM;             // 157
  const int gx2 = (TC * NN + TBM - 1) / TBM;        // 313
  for (int tcb = 0; tcb < TT / TC; tcb++) {
    k_proj<<<dim3(NN / 16, TC), 256, 0, stream>>>(
        xs, xd + (size_t)(tcb * TC) * NN * DDIM, projW, projb, hbf);
    for (int l = 0; l < NL; l++) {
      k_bgemm_gat<<<dim3(gx2, 2), 256, 0, stream>>>(
          hbf, gatWbf + (size_t)l * 128 * 128,
          attS + l * HEADS * DPH, attD + l * HEADS * DPH,
          xpbf, asrc, adst, TC * NN);
      k_aggr<<<TC * NN / 4, 256, 0, stream>>>(
          xpbf, hbf, asrc, adst, rowptr, col, gatb + (size_t)l * HID,
          lng + (size_t)l * HID, lnb + (size_t)l * HID);
    }
    for (int s2 = 0; s2 < TC; s2++) {
      int t = tcb * TC + s2;
      int pi = t & 1;
      k_bgemm_lstm<<<dim3(gx, 8), 256, 0, stream>>>(
          hbf + (size_t)s2 * NN * HID, h0buf[pi], Wc0bf, bs0, c0, h0buf[pi ^ 1], NN);
      k_bgemm_lstm<<<dim3(gx, 8), 256, 0, stream>>>(
          h0buf[pi ^ 1], h1buf[pi], Wc1bf, bs1, c1, h1buf[pi ^ 1], NN);
    }
  }

  // TT even -> final h1 lives in h1buf[0]
  k_mlp<<<NN, 64, 0, stream>>>(h1buf[0], oW1, ob1, oW2, ob2, out);
}